// Round 4
// baseline (311.299 us; speedup 1.0000x reference)
//
#include <hip/hip_runtime.h>
#include <hip/hip_bf16.h>

#define DIM    1024
#define NHEADS 16
#define HDIM   64
#define BB     2
#define SS     2048
#define MTOT   (BB * SS)  // 4096

typedef unsigned short u16;
typedef __attribute__((ext_vector_type(8))) short short8;   // 8 bf16 = 4 VGPR (MFMA A/B frag)
typedef __attribute__((ext_vector_type(4))) float f32x4;    // MFMA C/D frag

__device__ inline u16 f2b(float f) {
  __hip_bfloat16 h = __float2bfloat16(f);
  return *reinterpret_cast<u16*>(&h);
}
__device__ inline f32x4 zero4() { f32x4 v = {0.f, 0.f, 0.f, 0.f}; return v; }

// async global->LDS, 16B per lane; LDS dest = wave-uniform base + lane*16
#define GLD_LDS16(GP, LP)                                                   \
  __builtin_amdgcn_global_load_lds(                                         \
      (const __attribute__((address_space(1))) unsigned int*)               \
          (unsigned long long)(const void*)(GP),                            \
      (__attribute__((address_space(3))) unsigned int*)                     \
          (unsigned int)(unsigned long long)(const void*)(LP),              \
      16, 0, 0)

#define QSCALE 0.18033688011112042f  // 0.125 * log2(e): exp2 domain, exact softmax

// ---------------------------------------------------------------------------
// cast fp32 -> bf16, 8 elems/thread
// ---------------------------------------------------------------------------
__global__ __launch_bounds__(256) void cast_bf16_kernel(
    const float* __restrict__ in, u16* __restrict__ out, int n8) {
  const int i = blockIdx.x * blockDim.x + threadIdx.x;
  if (i >= n8) return;
  const float4 a = ((const float4*)in)[i * 2];
  const float4 b = ((const float4*)in)[i * 2 + 1];
  union { u16 u[8]; uint4 v; } r;
  r.u[0] = f2b(a.x); r.u[1] = f2b(a.y); r.u[2] = f2b(a.z); r.u[3] = f2b(a.w);
  r.u[4] = f2b(b.x); r.u[5] = f2b(b.y); r.u[6] = f2b(b.z); r.u[7] = f2b(b.w);
  ((uint4*)out)[i] = r.v;
}

// ---------------------------------------------------------------------------
// transpose+cast: in [K][N] fp32 -> out [N][K] bf16, 32x32 tiles
// ---------------------------------------------------------------------------
__global__ __launch_bounds__(256) void transpose_cast_kernel(
    const float* __restrict__ in, u16* __restrict__ out, int K, int N) {
  __shared__ u16 tile[32][36];
  const int t   = threadIdx.x;
  const int n0  = blockIdx.x * 32, k0 = blockIdx.y * 32;
  const int tr  = t >> 3, tc4 = (t & 7) * 4;
  const float4 a = *(const float4*)&in[(size_t)(k0 + tr) * N + n0 + tc4];
  tile[tr][tc4 + 0] = f2b(a.x); tile[tr][tc4 + 1] = f2b(a.y);
  tile[tr][tc4 + 2] = f2b(a.z); tile[tr][tc4 + 3] = f2b(a.w);
  __syncthreads();
  union { u16 u[4]; uint2 v; } pk;
  pk.u[0] = tile[tc4 + 0][tr]; pk.u[1] = tile[tc4 + 1][tr];
  pk.u[2] = tile[tc4 + 2][tr]; pk.u[3] = tile[tc4 + 3][tr];
  *(uint2*)&out[(size_t)(n0 + tr) * K + k0 + tc4] = pk.v;
}

// ---------------------------------------------------------------------------
// V transpose (bf16): v [bh][S][64] -> vt [bh][64][S], 64x64 tiles
// ---------------------------------------------------------------------------
__global__ __launch_bounds__(256) void vtrans_kernel(
    const u16* __restrict__ v, u16* __restrict__ vt) {
  __shared__ __align__(16) u16 tile[64][72];
  const int t  = threadIdx.x;
  const int s0 = blockIdx.x * 64, bh = blockIdx.y;
#pragma unroll
  for (int it = 0; it < 2; ++it) {
    const int ci = t + it * 256;
    const int sr = ci >> 3, c8 = (ci & 7) * 8;
    *(uint4*)&tile[sr][c8] =
        *(const uint4*)&v[((size_t)(bh * SS + s0 + sr)) * 64 + c8];
  }
  __syncthreads();
#pragma unroll
  for (int it = 0; it < 2; ++it) {
    const int ci = t + it * 256;
    const int h = ci >> 3, sc = (ci & 7) * 8;
    union { u16 u[8]; uint4 q; } pk;
#pragma unroll
    for (int j = 0; j < 8; ++j) pk.u[j] = tile[sc + j][h];
    *(uint4*)&vt[((size_t)(bh * 64 + h)) * SS + s0 + sc] = pk.q;
  }
}

// ---------------------------------------------------------------------------
// QKV GEMM bf16 MFMA: xa [4096][1024] x wt [3072][1024](=w^T) + bias
//  -> q/k/v [bh][S][64] bf16; q pre-scaled by 0.125*log2e (exp2-domain softmax).
// 128x128 tile, BK=64, 4 waves (2x2). XCD-swizzled 1D grid (768 = 8*96).
// ---------------------------------------------------------------------------
__global__ __launch_bounds__(256) void gemm_qkv_bf16(
    const u16* __restrict__ xa, const u16* __restrict__ wt,
    const float* __restrict__ bias,
    u16* __restrict__ qbuf, u16* __restrict__ kbuf, u16* __restrict__ vbuf) {
  __shared__ __align__(16) u16 As[128 * 64];
  __shared__ __align__(16) u16 Bs[128 * 64];
  const int tid = threadIdx.x, w = tid >> 6, lane = tid & 63;
  const int l15 = lane & 15, l4 = lane >> 4;
  const int lin = blockIdx.x;
  const int swz = (lin & 7) * 96 + (lin >> 3);   // XCD chunk = 3 n-bands x 32 m
  const int m0 = (swz & 31) * 128, n0 = (swz >> 5) * 128;
  const int wm = (w >> 1) * 64, wn = (w & 1) * 64;

  f32x4 acc[4][4];
#pragma unroll
  for (int i = 0; i < 4; ++i)
#pragma unroll
    for (int j = 0; j < 4; ++j) acc[i][j] = zero4();

  for (int k0 = 0; k0 < DIM; k0 += 64) {
#pragma unroll
    for (int j = 0; j < 4; ++j) {
      const int rowX = (w * 4 + j) * 8 + (lane >> 3);
      const int kcol = k0 + (lane & 7) * 8;
      GLD_LDS16(&xa[(size_t)(m0 + rowX) * DIM + kcol], &As[(w * 4 + j) * 512]);
      GLD_LDS16(&wt[(size_t)(n0 + rowX) * DIM + kcol], &Bs[(w * 4 + j) * 512]);
    }
    asm volatile("s_waitcnt vmcnt(0)" ::: "memory");
    __syncthreads();
#pragma unroll
    for (int kc = 0; kc < 2; ++kc) {
      short8 af[4], bfr[4];
#pragma unroll
      for (int mb = 0; mb < 4; ++mb)
        af[mb] = *(const short8*)&As[(wm + mb * 16 + l15) * 64 + kc * 32 + l4 * 8];
#pragma unroll
      for (int nb = 0; nb < 4; ++nb)
        bfr[nb] = *(const short8*)&Bs[(wn + nb * 16 + l15) * 64 + kc * 32 + l4 * 8];
#pragma unroll
      for (int mb = 0; mb < 4; ++mb)
#pragma unroll
        for (int nb = 0; nb < 4; ++nb)
          acc[mb][nb] = __builtin_amdgcn_mfma_f32_16x16x32_bf16(
              af[mb], bfr[nb], acc[mb][nb], 0, 0, 0);
    }
    __syncthreads();
  }

  const int colb  = n0 + wn;
  const int which = colb >> 10;
  const int head  = (colb >> 6) & 15;
  u16* __restrict__ dst = (which == 0) ? qbuf : (which == 1 ? kbuf : vbuf);
  const float scale = (which == 0) ? QSCALE : 1.0f;
#pragma unroll
  for (int nb = 0; nb < 4; ++nb) {
    const int col = colb + nb * 16 + l15;
    const float bv = bias[col];
    const int h = col & 63;
#pragma unroll
    for (int mb = 0; mb < 4; ++mb)
#pragma unroll
      for (int r = 0; r < 4; ++r) {
        const int row = m0 + wm + mb * 16 + l4 * 4 + r;
        const int b = row >> 11, s = row & 2047;
        dst[((size_t)((b * NHEADS + head) * SS + s)) * 64 + h] =
            f2b((acc[mb][nb][r] + bv) * scale);
      }
  }
}

// ---------------------------------------------------------------------------
// Flash attention bf16 MFMA, swapped operands + async double-buffer.
// Block = 256 thr / 4 waves; wave w owns q-rows qt*64+w*16+l15 (q = lane&15).
// S^T = mfma(K,Q): per-lane q=l15, 16 keys in (nb,r) -> m,l are lane-scalar.
// O^T = mfma(V,P): P fed as B-operand straight from 4x ds_write_b64.
// K/V double-buffered; tile t+2 global loads issued each iter (T14).
// exp2-domain softmax (Q pre-scaled); defer-max rescale (T13, THR=8).
// ---------------------------------------------------------------------------
__global__ __launch_bounds__(256) void attn_mfma(
    const u16* __restrict__ qbuf, const u16* __restrict__ kbuf,
    const u16* __restrict__ vtbuf, u16* __restrict__ aobuf) {
  __shared__ __align__(16) u16 Ks[2][64 * 64];
  __shared__ __align__(16) u16 Vs[2][64 * 64];
  __shared__ __align__(16) u16 Ps[4][16 * 64];
  const int tid = threadIdx.x, w = tid >> 6, lane = tid & 63;
  const int l15 = lane & 15, l4 = lane >> 4;
  const int lin = blockIdx.x;
  const int swz = (lin & 7) * 128 + (lin >> 3);  // XCD chunk = 4 bh x 32 qt
  const int bh = swz >> 5, qt = swz & 31;
  const int b = bh >> 4, head = bh & 15;

  const u16* __restrict__ qsrc  = qbuf + ((size_t)(bh * SS + qt * 64 + w * 16)) * 64;
  const u16* __restrict__ kbase = kbuf + (size_t)bh * SS * 64;
  const u16* __restrict__ vtb   = vtbuf + (size_t)bh * 64 * SS;

  short8 qf[2];
#pragma unroll
  for (int kc = 0; kc < 2; ++kc)
    qf[kc] = *(const short8*)&qsrc[l15 * 64 + kc * 32 + l4 * 8];

  // staging coords: thread covers K rows {row,row+32} and Vt rows {row,row+32}
  const int srow = tid >> 3, sc8 = tid & 7;
  const int ssw  = (sc8 ^ (srow & 7)) * 8;
  uint4 kreg[2], vreg[2];

#define LOADT(t)                                                              \
  {                                                                           \
    const u16* kp = kbase + ((size_t)((t) * 64 + srow)) * 64 + sc8 * 8;       \
    kreg[0] = *(const uint4*)kp;                                              \
    kreg[1] = *(const uint4*)(kp + 32 * 64);                                  \
    const u16* vp = vtb + (size_t)srow * SS + (t) * 64 + sc8 * 8;             \
    vreg[0] = *(const uint4*)vp;                                              \
    vreg[1] = *(const uint4*)(vp + 32 * SS);                                  \
  }
#define WRITET(bi)                                                            \
  {                                                                           \
    u16* kd = &Ks[bi][srow * 64 + ssw];                                       \
    *(uint4*)kd = kreg[0];                                                    \
    *(uint4*)(kd + 32 * 64) = kreg[1];                                        \
    u16* vd = &Vs[bi][srow * 64 + ssw];                                       \
    *(uint4*)vd = vreg[0];                                                    \
    *(uint4*)(vd + 32 * 64) = vreg[1];                                        \
  }

  LOADT(0);
  WRITET(0);
  LOADT(1);
  __syncthreads();

  f32x4 acco[4];
#pragma unroll
  for (int i = 0; i < 4; ++i) acco[i] = zero4();
  float mrun = -1e30f, lrun = 0.f;

  for (int kt = 0; kt < SS / 64; ++kt) {
    const int cur = kt & 1;

    // S^T = mfma(K, Q): lane q=l15, keys nb*16 + l4*4 + r
    f32x4 sc[4];
#pragma unroll
    for (int i = 0; i < 4; ++i) sc[i] = zero4();
#pragma unroll
    for (int kc = 0; kc < 2; ++kc)
#pragma unroll
      for (int nb = 0; nb < 4; ++nb) {
        const int key = nb * 16 + l15;
        const int cc = (kc * 4 + l4) ^ (l15 & 7);
        const short8 kf = *(const short8*)&Ks[cur][key * 64 + cc * 8];
        sc[nb] = __builtin_amdgcn_mfma_f32_16x16x32_bf16(kf, qf[kc], sc[nb], 0, 0, 0);
      }

    // lane-scalar online softmax (exp2 domain)
    float tmax = sc[0][0];
#pragma unroll
    for (int nb = 0; nb < 4; ++nb)
#pragma unroll
      for (int r = 0; r < 4; ++r) tmax = fmaxf(tmax, sc[nb][r]);
    tmax = fmaxf(tmax, __shfl_xor(tmax, 16));
    tmax = fmaxf(tmax, __shfl_xor(tmax, 32));
    if (__ballot(tmax > mrun + 8.0f)) {   // defer-max: rescale only on real growth
      const float mnew = fmaxf(mrun, tmax);
      const float f = exp2f(mrun - mnew);
      mrun = mnew;
      lrun *= f;
#pragma unroll
      for (int nb = 0; nb < 4; ++nb)
#pragma unroll
        for (int r = 0; r < 4; ++r) acco[nb][r] *= f;
    }
    float p[4][4], rs = 0.f;
#pragma unroll
    for (int nb = 0; nb < 4; ++nb)
#pragma unroll
      for (int r = 0; r < 4; ++r) {
        p[nb][r] = exp2f(sc[nb][r] - mrun);
        rs += p[nb][r];
      }
    rs += __shfl_xor(rs, 16);
    rs += __shfl_xor(rs, 32);
    lrun += rs;

    // P -> LDS: 4 consecutive keys per write (swizzled b64)
#pragma unroll
    for (int nb = 0; nb < 4; ++nb) {
      union { u16 u[4]; uint2 v; } pk;
#pragma unroll
      for (int r = 0; r < 4; ++r) pk.u[r] = f2b(p[nb][r]);
      const int cc = (nb * 2 + (l4 >> 1)) ^ (l15 & 7);
      *(uint2*)&Ps[w][l15 * 64 + cc * 8 + (l4 & 1) * 4] = pk.v;
    }

    // O^T += mfma(V, P)
#pragma unroll
    for (int kc = 0; kc < 2; ++kc) {
      const int ccp = (kc * 4 + l4) ^ (l15 & 7);
      const short8 pf = *(const short8*)&Ps[w][l15 * 64 + ccp * 8];
#pragma unroll
      for (int nb = 0; nb < 4; ++nb) {
        const int h = nb * 16 + l15;
        const int cv = (kc * 4 + l4) ^ (l15 & 7);
        const short8 vf = *(const short8*)&Vs[cur][h * 64 + cv * 8];
        acco[nb] = __builtin_amdgcn_mfma_f32_16x16x32_bf16(vf, pf, acco[nb], 0, 0, 0);
      }
    }

    // stage tile kt+1 into the other buffer; issue loads for kt+2
    if (kt < SS / 64 - 1) WRITET(1 - cur);
    if (kt < SS / 64 - 2) LOADT(kt + 2);
    __syncthreads();
  }
#undef LOADT
#undef WRITET

  // epilogue: O[q=l15][h=nb*16+l4*4+r] / lrun -> ao [4096][1024] bf16
  const float inv = 1.f / lrun;
  const int s = qt * 64 + w * 16 + l15;
  u16* __restrict__ dst = aobuf + (size_t)(b * SS + s) * DIM + head * 64;
#pragma unroll
  for (int nb = 0; nb < 4; ++nb) {
    union { u16 u[4]; uint2 v; } pk;
#pragma unroll
    for (int r = 0; r < 4; ++r) pk.u[r] = f2b(acco[nb][r] * inv);
    *(uint2*)&dst[nb * 16 + l4 * 4] = pk.v;
  }
}

// ---------------------------------------------------------------------------
// Proj GEMM bf16 MFMA: ao [4096][1024] x wpt [1024][1024](=w^T) + bias -> fp32
// XCD-swizzled 1D grid (256 = 8*32).
// ---------------------------------------------------------------------------
__global__ __launch_bounds__(256) void gemm_proj_bf16(
    const u16* __restrict__ ao, const u16* __restrict__ wpt,
    const float* __restrict__ bias, float* __restrict__ out) {
  __shared__ __align__(16) u16 As[128 * 64];
  __shared__ __align__(16) u16 Bs[128 * 64];
  const int tid = threadIdx.x, w = tid >> 6, lane = tid & 63;
  const int l15 = lane & 15, l4 = lane >> 4;
  const int lin = blockIdx.x;
  const int swz = (lin & 7) * 32 + (lin >> 3);
  const int m0 = (swz & 31) * 128, n0 = (swz >> 5) * 128;
  const int wm = (w >> 1) * 64, wn = (w & 1) * 64;

  f32x4 acc[4][4];
#pragma unroll
  for (int i = 0; i < 4; ++i)
#pragma unroll
    for (int j = 0; j < 4; ++j) acc[i][j] = zero4();

  for (int k0 = 0; k0 < DIM; k0 += 64) {
#pragma unroll
    for (int j = 0; j < 4; ++j) {
      const int rowX = (w * 4 + j) * 8 + (lane >> 3);
      const int kcol = k0 + (lane & 7) * 8;
      GLD_LDS16(&ao[(size_t)(m0 + rowX) * DIM + kcol], &As[(w * 4 + j) * 512]);
      GLD_LDS16(&wpt[(size_t)(n0 + rowX) * DIM + kcol], &Bs[(w * 4 + j) * 512]);
    }
    asm volatile("s_waitcnt vmcnt(0)" ::: "memory");
    __syncthreads();
#pragma unroll
    for (int kc = 0; kc < 2; ++kc) {
      short8 af[4], bfr[4];
#pragma unroll
      for (int mb = 0; mb < 4; ++mb)
        af[mb] = *(const short8*)&As[(wm + mb * 16 + l15) * 64 + kc * 32 + l4 * 8];
#pragma unroll
      for (int nb = 0; nb < 4; ++nb)
        bfr[nb] = *(const short8*)&Bs[(wn + nb * 16 + l15) * 64 + kc * 32 + l4 * 8];
#pragma unroll
      for (int mb = 0; mb < 4; ++mb)
#pragma unroll
        for (int nb = 0; nb < 4; ++nb)
          acc[mb][nb] = __builtin_amdgcn_mfma_f32_16x16x32_bf16(
              af[mb], bfr[nb], acc[mb][nb], 0, 0, 0);
    }
    __syncthreads();
  }
#pragma unroll
  for (int nb = 0; nb < 4; ++nb) {
    const int col = n0 + wn + nb * 16 + l15;
    const float bv = bias[col];
#pragma unroll
    for (int mb = 0; mb < 4; ++mb)
#pragma unroll
      for (int r = 0; r < 4; ++r) {
        const int row = m0 + wm + mb * 16 + l4 * 4 + r;
        out[(size_t)row * DIM + col] = acc[mb][nb][r] + bv;
      }
  }
}

// ---------------------------------------------------------------------------
extern "C" void kernel_launch(void* const* d_in, const int* in_sizes, int n_in,
                              void* d_out, int out_size, void* d_ws, size_t ws_size,
                              hipStream_t stream) {
  const float* x      = (const float*)d_in[0];
  const float* w_qkv  = (const float*)d_in[1];
  const float* b_qkv  = (const float*)d_in[2];
  const float* w_proj = (const float*)d_in[3];
  const float* b_proj = (const float*)d_in[4];
  float* out = (float*)d_out;

  u16* ws = (u16*)d_ws;
  u16* x_bf    = ws;                               // 4096*1024
  u16* wqkv_t  = x_bf   + (size_t)MTOT * DIM;      // 3072*1024
  u16* wproj_t = wqkv_t + (size_t)3 * DIM * DIM;   // 1024*1024
  u16* qbuf    = wproj_t + (size_t)DIM * DIM;      // 32*2048*64
  u16* kbuf    = qbuf + (size_t)MTOT * DIM;
  u16* vbuf    = kbuf + (size_t)MTOT * DIM;
  u16* vtbuf   = vbuf + (size_t)MTOT * DIM;
  u16* aobuf   = vtbuf + (size_t)MTOT * DIM;

  cast_bf16_kernel<<<2048, 256, 0, stream>>>(x, x_bf, MTOT * DIM / 8);
  transpose_cast_kernel<<<dim3(96, 32), 256, 0, stream>>>(w_qkv, wqkv_t, DIM, 3 * DIM);
  transpose_cast_kernel<<<dim3(32, 32), 256, 0, stream>>>(w_proj, wproj_t, DIM, DIM);
  gemm_qkv_bf16<<<768, 256, 0, stream>>>(x_bf, wqkv_t, b_qkv, qbuf, kbuf, vbuf);
  vtrans_kernel<<<dim3(32, 32), 256, 0, stream>>>(vbuf, vtbuf);
  attn_mfma<<<1024, 256, 0, stream>>>(qbuf, kbuf, vtbuf, aobuf);
  gemm_proj_bf16<<<256, 256, 0, stream>>>(aobuf, wproj_t, b_proj, out);
}

// Round 5
// 239.310 us; speedup vs baseline: 1.3008x; 1.3008x over previous
//
#include <hip/hip_runtime.h>
#include <hip/hip_bf16.h>

#define DIM    1024
#define NHEADS 16
#define HDIM   64
#define BB     2
#define SS     2048
#define MTOT   (BB * SS)  // 4096

typedef unsigned short u16;
typedef __attribute__((ext_vector_type(8))) short short8;   // 8 bf16 = 4 VGPR (MFMA A/B frag)
typedef __attribute__((ext_vector_type(4))) float f32x4;    // MFMA C/D frag

__device__ inline u16 f2b(float f) {
  __hip_bfloat16 h = __float2bfloat16(f);
  return *reinterpret_cast<u16*>(&h);
}
__device__ inline f32x4 zero4() { f32x4 v = {0.f, 0.f, 0.f, 0.f}; return v; }

// async global->LDS, 16B per lane; LDS dest = wave-uniform base + lane*16
#define GLD_LDS16(GP, LP)                                                   \
  __builtin_amdgcn_global_load_lds(                                         \
      (const __attribute__((address_space(1))) unsigned int*)               \
          (unsigned long long)(const void*)(GP),                            \
      (__attribute__((address_space(3))) unsigned int*)                     \
          (unsigned int)(unsigned long long)(const void*)(LP),              \
      16, 0, 0)

#define QSCALE 0.18033688011112042f  // 0.125 * log2(e): exp2 domain, exact softmax

// ---------------------------------------------------------------------------
// cast fp32 -> bf16, 8 elems/thread
// ---------------------------------------------------------------------------
__global__ __launch_bounds__(256) void cast_bf16_kernel(
    const float* __restrict__ in, u16* __restrict__ out, int n8) {
  const int i = blockIdx.x * blockDim.x + threadIdx.x;
  if (i >= n8) return;
  const float4 a = ((const float4*)in)[i * 2];
  const float4 b = ((const float4*)in)[i * 2 + 1];
  union { u16 u[8]; uint4 v; } r;
  r.u[0] = f2b(a.x); r.u[1] = f2b(a.y); r.u[2] = f2b(a.z); r.u[3] = f2b(a.w);
  r.u[4] = f2b(b.x); r.u[5] = f2b(b.y); r.u[6] = f2b(b.z); r.u[7] = f2b(b.w);
  ((uint4*)out)[i] = r.v;
}

// ---------------------------------------------------------------------------
// transpose+cast: in [K][N] fp32 -> out [N][K] bf16, 32x32 tiles
// ---------------------------------------------------------------------------
__global__ __launch_bounds__(256) void transpose_cast_kernel(
    const float* __restrict__ in, u16* __restrict__ out, int K, int N) {
  __shared__ u16 tile[32][36];
  const int t   = threadIdx.x;
  const int n0  = blockIdx.x * 32, k0 = blockIdx.y * 32;
  const int tr  = t >> 3, tc4 = (t & 7) * 4;
  const float4 a = *(const float4*)&in[(size_t)(k0 + tr) * N + n0 + tc4];
  tile[tr][tc4 + 0] = f2b(a.x); tile[tr][tc4 + 1] = f2b(a.y);
  tile[tr][tc4 + 2] = f2b(a.z); tile[tr][tc4 + 3] = f2b(a.w);
  __syncthreads();
  union { u16 u[4]; uint2 v; } pk;
  pk.u[0] = tile[tc4 + 0][tr]; pk.u[1] = tile[tc4 + 1][tr];
  pk.u[2] = tile[tc4 + 2][tr]; pk.u[3] = tile[tc4 + 3][tr];
  *(uint2*)&out[(size_t)(n0 + tr) * K + k0 + tc4] = pk.v;
}

// ---------------------------------------------------------------------------
// V transpose (bf16): v [bh][S][64] -> vt [bh][64][S], 64x64 tiles
// ---------------------------------------------------------------------------
__global__ __launch_bounds__(256) void vtrans_kernel(
    const u16* __restrict__ v, u16* __restrict__ vt) {
  __shared__ __align__(16) u16 tile[64][72];
  const int t  = threadIdx.x;
  const int s0 = blockIdx.x * 64, bh = blockIdx.y;
#pragma unroll
  for (int it = 0; it < 2; ++it) {
    const int ci = t + it * 256;
    const int sr = ci >> 3, c8 = (ci & 7) * 8;
    *(uint4*)&tile[sr][c8] =
        *(const uint4*)&v[((size_t)(bh * SS + s0 + sr)) * 64 + c8];
  }
  __syncthreads();
#pragma unroll
  for (int it = 0; it < 2; ++it) {
    const int ci = t + it * 256;
    const int h = ci >> 3, sc = (ci & 7) * 8;
    union { u16 u[8]; uint4 q; } pk;
#pragma unroll
    for (int j = 0; j < 8; ++j) pk.u[j] = tile[sc + j][h];
    *(uint4*)&vt[((size_t)(bh * 64 + h)) * SS + s0 + sc] = pk.q;
  }
}

// ---------------------------------------------------------------------------
// QKV GEMM bf16 MFMA: xa [4096][1024] x wt [3072][1024](=w^T) + bias
//  -> q/k/v [bh][S][64] bf16; q pre-scaled by 0.125*log2e (exp2-domain softmax).
// 128x128 tile, BK=64, 4 waves (2x2). XCD-swizzled 1D grid (768 = 8*96).
// ---------------------------------------------------------------------------
__global__ __launch_bounds__(256) void gemm_qkv_bf16(
    const u16* __restrict__ xa, const u16* __restrict__ wt,
    const float* __restrict__ bias,
    u16* __restrict__ qbuf, u16* __restrict__ kbuf, u16* __restrict__ vbuf) {
  __shared__ __align__(16) u16 As[128 * 64];
  __shared__ __align__(16) u16 Bs[128 * 64];
  const int tid = threadIdx.x, w = tid >> 6, lane = tid & 63;
  const int l15 = lane & 15, l4 = lane >> 4;
  const int lin = blockIdx.x;
  const int swz = (lin & 7) * 96 + (lin >> 3);   // XCD chunk = 3 n-bands x 32 m
  const int m0 = (swz & 31) * 128, n0 = (swz >> 5) * 128;
  const int wm = (w >> 1) * 64, wn = (w & 1) * 64;

  f32x4 acc[4][4];
#pragma unroll
  for (int i = 0; i < 4; ++i)
#pragma unroll
    for (int j = 0; j < 4; ++j) acc[i][j] = zero4();

  for (int k0 = 0; k0 < DIM; k0 += 64) {
#pragma unroll
    for (int j = 0; j < 4; ++j) {
      const int rowX = (w * 4 + j) * 8 + (lane >> 3);
      const int kcol = k0 + (lane & 7) * 8;
      GLD_LDS16(&xa[(size_t)(m0 + rowX) * DIM + kcol], &As[(w * 4 + j) * 512]);
      GLD_LDS16(&wt[(size_t)(n0 + rowX) * DIM + kcol], &Bs[(w * 4 + j) * 512]);
    }
    asm volatile("s_waitcnt vmcnt(0)" ::: "memory");
    __syncthreads();
#pragma unroll
    for (int kc = 0; kc < 2; ++kc) {
      short8 af[4], bfr[4];
#pragma unroll
      for (int mb = 0; mb < 4; ++mb)
        af[mb] = *(const short8*)&As[(wm + mb * 16 + l15) * 64 + kc * 32 + l4 * 8];
#pragma unroll
      for (int nb = 0; nb < 4; ++nb)
        bfr[nb] = *(const short8*)&Bs[(wn + nb * 16 + l15) * 64 + kc * 32 + l4 * 8];
#pragma unroll
      for (int mb = 0; mb < 4; ++mb)
#pragma unroll
        for (int nb = 0; nb < 4; ++nb)
          acc[mb][nb] = __builtin_amdgcn_mfma_f32_16x16x32_bf16(
              af[mb], bfr[nb], acc[mb][nb], 0, 0, 0);
    }
    __syncthreads();
  }

  const int colb  = n0 + wn;
  const int which = colb >> 10;
  const int head  = (colb >> 6) & 15;
  u16* __restrict__ dst = (which == 0) ? qbuf : (which == 1 ? kbuf : vbuf);
  const float scale = (which == 0) ? QSCALE : 1.0f;
#pragma unroll
  for (int nb = 0; nb < 4; ++nb) {
    const int col = colb + nb * 16 + l15;
    const float bv = bias[col];
    const int h = col & 63;
#pragma unroll
    for (int mb = 0; mb < 4; ++mb)
#pragma unroll
      for (int r = 0; r < 4; ++r) {
        const int row = m0 + wm + mb * 16 + l4 * 4 + r;
        const int b = row >> 11, s = row & 2047;
        dst[((size_t)((b * NHEADS + head) * SS + s)) * 64 + h] =
            f2b((acc[mb][nb][r] + bv) * scale);
      }
  }
}

// ---------------------------------------------------------------------------
// Flash attention bf16 MFMA v3: swapped operands + gld_lds double-buffer.
// Block = 256 thr / 4 waves; wave w owns q-rows qt*64+w*16+l15 (q = lane&15).
// S^T = mfma(K,Q); O^T = mfma(V,P).
// K/V staged via global_load_lds (zero VGPR staging cost — R3's reg-staging
// spilled: WRITE_SIZE 290MB of scratch traffic). Swizzle applied on the
// GLOBAL source address (linear LDS dest; rule #21); reads unchanged.
// 2-phase pipeline: issue tile t+1 DMA, compute tile t, vmcnt(0)+barrier.
// exp2-domain softmax (Q pre-scaled); defer-max rescale (T13, THR=8).
// __launch_bounds__(256,4): 4 blocks/CU (LDS-bound anyway) -> VGPR cap 128,
// forbids the spill-for-occupancy heuristic that caused R3's regression.
// ---------------------------------------------------------------------------
__global__ __launch_bounds__(256, 4) void attn_mfma(
    const u16* __restrict__ qbuf, const u16* __restrict__ kbuf,
    const u16* __restrict__ vtbuf, u16* __restrict__ aobuf) {
  __shared__ __align__(16) u16 Ks[2][64 * 64];
  __shared__ __align__(16) u16 Vs[2][64 * 64];
  __shared__ __align__(16) u16 Ps[4][16 * 64];
  const int tid = threadIdx.x, w = tid >> 6, lane = tid & 63;
  const int l15 = lane & 15, l4 = lane >> 4;
  const int lin = blockIdx.x;
  const int swz = (lin & 7) * 128 + (lin >> 3);  // XCD chunk = 4 bh x 32 qt
  const int bh = swz >> 5, qt = swz & 31;
  const int b = bh >> 4, head = bh & 15;

  const u16* __restrict__ qsrc  = qbuf + ((size_t)(bh * SS + qt * 64 + w * 16)) * 64;
  const u16* __restrict__ kbase = kbuf + (size_t)bh * SS * 64;
  const u16* __restrict__ vtb   = vtbuf + (size_t)bh * 64 * SS;

  short8 qf[2];
#pragma unroll
  for (int kc = 0; kc < 2; ++kc)
    qf[kc] = *(const short8*)&qsrc[l15 * 64 + kc * 32 + l4 * 8];

  // DMA staging: wave w covers rows [w*16, w*16+16) of K and Vt tiles.
  // Lane l covers row w*16 + j*8 + (l>>3), 16B chunk (l&7), with the XOR
  // swizzle folded into the SOURCE chunk index (LDS dest stays linear:
  // LDS[row][d] ends up holding global chunk d ^ (row&7), same as R3).
  const int srow8 = lane >> 3;           // 0..7  (== row & 7)
  const int schk  = (lane & 7) ^ srow8;  // swizzled source 16B-chunk

#define STAGE(t, bi)                                                          \
  {                                                                           \
    const int r0 = w * 16;                                                    \
    const u16* kp = kbase + ((size_t)((t) * 64 + r0 + srow8)) * 64 + schk * 8;\
    GLD_LDS16(kp,          &Ks[bi][r0 * 64]);                                 \
    GLD_LDS16(kp + 8 * 64, &Ks[bi][(r0 + 8) * 64]);                           \
    const u16* vp = vtb + (size_t)(r0 + srow8) * SS + (t) * 64 + schk * 8;    \
    GLD_LDS16(vp,          &Vs[bi][r0 * 64]);                                 \
    GLD_LDS16(vp + 8 * SS, &Vs[bi][(r0 + 8) * 64]);                           \
  }

  STAGE(0, 0);
  asm volatile("s_waitcnt vmcnt(0)" ::: "memory");
  __syncthreads();

  f32x4 acco[4];
#pragma unroll
  for (int i = 0; i < 4; ++i) acco[i] = zero4();
  float mrun = -1e30f, lrun = 0.f;

  for (int kt = 0; kt < SS / 64; ++kt) {
    const int cur = kt & 1;

    // issue next tile's DMA into the other buffer (flies under compute)
    if (kt + 1 < SS / 64) STAGE(kt + 1, 1 - cur);

    // S^T = mfma(K, Q): lane q=l15, keys nb*16 + l4*4 + r
    f32x4 sc[4];
#pragma unroll
    for (int i = 0; i < 4; ++i) sc[i] = zero4();
#pragma unroll
    for (int kc = 0; kc < 2; ++kc)
#pragma unroll
      for (int nb = 0; nb < 4; ++nb) {
        const int key = nb * 16 + l15;
        const int cc = (kc * 4 + l4) ^ (l15 & 7);
        const short8 kf = *(const short8*)&Ks[cur][key * 64 + cc * 8];
        sc[nb] = __builtin_amdgcn_mfma_f32_16x16x32_bf16(kf, qf[kc], sc[nb], 0, 0, 0);
      }

    // lane-scalar online softmax (exp2 domain)
    float tmax = sc[0][0];
#pragma unroll
    for (int nb = 0; nb < 4; ++nb)
#pragma unroll
      for (int r = 0; r < 4; ++r) tmax = fmaxf(tmax, sc[nb][r]);
    tmax = fmaxf(tmax, __shfl_xor(tmax, 16));
    tmax = fmaxf(tmax, __shfl_xor(tmax, 32));
    if (__ballot(tmax > mrun + 8.0f)) {   // defer-max: rescale only on real growth
      const float mnew = fmaxf(mrun, tmax);
      const float f = exp2f(mrun - mnew);
      mrun = mnew;
      lrun *= f;
#pragma unroll
      for (int nb = 0; nb < 4; ++nb)
#pragma unroll
        for (int r = 0; r < 4; ++r) acco[nb][r] *= f;
    }
    float p[4][4], rs = 0.f;
#pragma unroll
    for (int nb = 0; nb < 4; ++nb)
#pragma unroll
      for (int r = 0; r < 4; ++r) {
        p[nb][r] = exp2f(sc[nb][r] - mrun);
        rs += p[nb][r];
      }
    rs += __shfl_xor(rs, 16);
    rs += __shfl_xor(rs, 32);
    lrun += rs;

    // P -> LDS: 4 consecutive keys per write (swizzled b64)
#pragma unroll
    for (int nb = 0; nb < 4; ++nb) {
      union { u16 u[4]; uint2 v; } pk;
#pragma unroll
      for (int r = 0; r < 4; ++r) pk.u[r] = f2b(p[nb][r]);
      const int cc = (nb * 2 + (l4 >> 1)) ^ (l15 & 7);
      *(uint2*)&Ps[w][l15 * 64 + cc * 8 + (l4 & 1) * 4] = pk.v;
    }

    // O^T += mfma(V, P)
#pragma unroll
    for (int kc = 0; kc < 2; ++kc) {
      const int ccp = (kc * 4 + l4) ^ (l15 & 7);
      const short8 pf = *(const short8*)&Ps[w][l15 * 64 + ccp * 8];
#pragma unroll
      for (int nb = 0; nb < 4; ++nb) {
        const int h = nb * 16 + l15;
        const int cv = (kc * 4 + l4) ^ (l15 & 7);
        const short8 vf = *(const short8*)&Vs[cur][h * 64 + cv * 8];
        acco[nb] = __builtin_amdgcn_mfma_f32_16x16x32_bf16(vf, pf, acco[nb], 0, 0, 0);
      }
    }

    // prefetch for tile kt+1 must have landed before next iteration reads it
    asm volatile("s_waitcnt vmcnt(0)" ::: "memory");
    __syncthreads();
  }
#undef STAGE

  // epilogue: O[q=l15][h=nb*16+l4*4+r] / lrun -> ao [4096][1024] bf16
  const float inv = 1.f / lrun;
  const int s = qt * 64 + w * 16 + l15;
  u16* __restrict__ dst = aobuf + (size_t)(b * SS + s) * DIM + head * 64;
#pragma unroll
  for (int nb = 0; nb < 4; ++nb) {
    union { u16 u[4]; uint2 v; } pk;
#pragma unroll
    for (int r = 0; r < 4; ++r) pk.u[r] = f2b(acco[nb][r] * inv);
    *(uint2*)&dst[nb * 16 + l4 * 4] = pk.v;
  }
}

// ---------------------------------------------------------------------------
// Proj GEMM bf16 MFMA: ao [4096][1024] x wpt [1024][1024](=w^T) + bias -> fp32
// XCD-swizzled 1D grid (256 = 8*32).
// ---------------------------------------------------------------------------
__global__ __launch_bounds__(256) void gemm_proj_bf16(
    const u16* __restrict__ ao, const u16* __restrict__ wpt,
    const float* __restrict__ bias, float* __restrict__ out) {
  __shared__ __align__(16) u16 As[128 * 64];
  __shared__ __align__(16) u16 Bs[128 * 64];
  const int tid = threadIdx.x, w = tid >> 6, lane = tid & 63;
  const int l15 = lane & 15, l4 = lane >> 4;
  const int lin = blockIdx.x;
  const int swz = (lin & 7) * 32 + (lin >> 3);
  const int m0 = (swz & 31) * 128, n0 = (swz >> 5) * 128;
  const int wm = (w >> 1) * 64, wn = (w & 1) * 64;

  f32x4 acc[4][4];
#pragma unroll
  for (int i = 0; i < 4; ++i)
#pragma unroll
    for (int j = 0; j < 4; ++j) acc[i][j] = zero4();

  for (int k0 = 0; k0 < DIM; k0 += 64) {
#pragma unroll
    for (int j = 0; j < 4; ++j) {
      const int rowX = (w * 4 + j) * 8 + (lane >> 3);
      const int kcol = k0 + (lane & 7) * 8;
      GLD_LDS16(&ao[(size_t)(m0 + rowX) * DIM + kcol], &As[(w * 4 + j) * 512]);
      GLD_LDS16(&wpt[(size_t)(n0 + rowX) * DIM + kcol], &Bs[(w * 4 + j) * 512]);
    }
    asm volatile("s_waitcnt vmcnt(0)" ::: "memory");
    __syncthreads();
#pragma unroll
    for (int kc = 0; kc < 2; ++kc) {
      short8 af[4], bfr[4];
#pragma unroll
      for (int mb = 0; mb < 4; ++mb)
        af[mb] = *(const short8*)&As[(wm + mb * 16 + l15) * 64 + kc * 32 + l4 * 8];
#pragma unroll
      for (int nb = 0; nb < 4; ++nb)
        bfr[nb] = *(const short8*)&Bs[(wn + nb * 16 + l15) * 64 + kc * 32 + l4 * 8];
#pragma unroll
      for (int mb = 0; mb < 4; ++mb)
#pragma unroll
        for (int nb = 0; nb < 4; ++nb)
          acc[mb][nb] = __builtin_amdgcn_mfma_f32_16x16x32_bf16(
              af[mb], bfr[nb], acc[mb][nb], 0, 0, 0);
    }
    __syncthreads();
  }
#pragma unroll
  for (int nb = 0; nb < 4; ++nb) {
    const int col = n0 + wn + nb * 16 + l15;
    const float bv = bias[col];
#pragma unroll
    for (int mb = 0; mb < 4; ++mb)
#pragma unroll
      for (int r = 0; r < 4; ++r) {
        const int row = m0 + wm + mb * 16 + l4 * 4 + r;
        out[(size_t)row * DIM + col] = acc[mb][nb][r] + bv;
      }
  }
}

// ---------------------------------------------------------------------------
extern "C" void kernel_launch(void* const* d_in, const int* in_sizes, int n_in,
                              void* d_out, int out_size, void* d_ws, size_t ws_size,
                              hipStream_t stream) {
  const float* x      = (const float*)d_in[0];
  const float* w_qkv  = (const float*)d_in[1];
  const float* b_qkv  = (const float*)d_in[2];
  const float* w_proj = (const float*)d_in[3];
  const float* b_proj = (const float*)d_in[4];
  float* out = (float*)d_out;

  u16* ws = (u16*)d_ws;
  u16* x_bf    = ws;                               // 4096*1024
  u16* wqkv_t  = x_bf   + (size_t)MTOT * DIM;      // 3072*1024
  u16* wproj_t = wqkv_t + (size_t)3 * DIM * DIM;   // 1024*1024
  u16* qbuf    = wproj_t + (size_t)DIM * DIM;      // 32*2048*64
  u16* kbuf    = qbuf + (size_t)MTOT * DIM;
  u16* vbuf    = kbuf + (size_t)MTOT * DIM;
  u16* vtbuf   = vbuf + (size_t)MTOT * DIM;
  u16* aobuf   = vtbuf + (size_t)MTOT * DIM;

  cast_bf16_kernel<<<2048, 256, 0, stream>>>(x, x_bf, MTOT * DIM / 8);
  transpose_cast_kernel<<<dim3(96, 32), 256, 0, stream>>>(w_qkv, wqkv_t, DIM, 3 * DIM);
  transpose_cast_kernel<<<dim3(32, 32), 256, 0, stream>>>(w_proj, wproj_t, DIM, DIM);
  gemm_qkv_bf16<<<768, 256, 0, stream>>>(x_bf, wqkv_t, b_qkv, qbuf, kbuf, vbuf);
  vtrans_kernel<<<dim3(32, 32), 256, 0, stream>>>(vbuf, vtbuf);
  attn_mfma<<<1024, 256, 0, stream>>>(qbuf, kbuf, vtbuf, aobuf);
  gemm_proj_bf16<<<256, 256, 0, stream>>>(aobuf, wproj_t, b_proj, out);
}

// Round 6
// 232.049 us; speedup vs baseline: 1.3415x; 1.0313x over previous
//
#include <hip/hip_runtime.h>
#include <hip/hip_bf16.h>

#define DIM    1024
#define NHEADS 16
#define HDIM   64
#define BB     2
#define SS     2048
#define MTOT   (BB * SS)  // 4096

typedef unsigned short u16;
typedef __attribute__((ext_vector_type(8))) short short8;   // 8 bf16 = 4 VGPR (MFMA A/B frag)
typedef __attribute__((ext_vector_type(4))) float f32x4;    // MFMA C/D frag

__device__ inline u16 f2b(float f) {
  __hip_bfloat16 h = __float2bfloat16(f);
  return *reinterpret_cast<u16*>(&h);
}
__device__ inline f32x4 zero4() { f32x4 v = {0.f, 0.f, 0.f, 0.f}; return v; }

// async global->LDS, 16B per lane; LDS dest = wave-uniform base + lane*16
#define GLD_LDS16(GP, LP)                                                   \
  __builtin_amdgcn_global_load_lds(                                         \
      (const __attribute__((address_space(1))) unsigned int*)               \
          (unsigned long long)(const void*)(GP),                            \
      (__attribute__((address_space(3))) unsigned int*)                     \
          (unsigned int)(unsigned long long)(const void*)(LP),              \
      16, 0, 0)

#define QSCALE 0.18033688011112042f  // 0.125 * log2(e): exp2 domain, exact softmax

// ---------------------------------------------------------------------------
// Fused prep: [0,2048)   cast x fp32->bf16 (8 elems/thread)
//             [2048,5120) transpose+cast w_qkv [1024][3072] -> [3072][1024]
//             [5120,6144) transpose+cast w_proj [1024][1024] -> [1024][1024]
// Branch is uniform per block; saves 2 kernel launches.
// ---------------------------------------------------------------------------
__global__ __launch_bounds__(256) void prep_kernel(
    const float* __restrict__ x, const float* __restrict__ wq,
    const float* __restrict__ wp,
    u16* __restrict__ x_bf, u16* __restrict__ wqt, u16* __restrict__ wpt) {
  __shared__ u16 tile[32][36];
  const int t   = threadIdx.x;
  const int blk = blockIdx.x;
  if (blk < 2048) {
    const int i = blk * 256 + t;
    const float4 a = ((const float4*)x)[i * 2];
    const float4 b = ((const float4*)x)[i * 2 + 1];
    union { u16 u[8]; uint4 v; } r;
    r.u[0] = f2b(a.x); r.u[1] = f2b(a.y); r.u[2] = f2b(a.z); r.u[3] = f2b(a.w);
    r.u[4] = f2b(b.x); r.u[5] = f2b(b.y); r.u[6] = f2b(b.z); r.u[7] = f2b(b.w);
    ((uint4*)x_bf)[i] = r.v;
    return;
  }
  const float* __restrict__ in;
  u16* __restrict__ out;
  int N, n0, k0;
  if (blk < 5120) {
    const int b2 = blk - 2048;
    in = wq; out = wqt; N = 3072;
    n0 = (b2 % 96) * 32; k0 = (b2 / 96) * 32;
  } else {
    const int b2 = blk - 5120;
    in = wp; out = wpt; N = 1024;
    n0 = (b2 & 31) * 32; k0 = (b2 >> 5) * 32;
  }
  const int tr = t >> 3, tc4 = (t & 7) * 4;
  const float4 a = *(const float4*)&in[(size_t)(k0 + tr) * N + n0 + tc4];
  tile[tr][tc4 + 0] = f2b(a.x); tile[tr][tc4 + 1] = f2b(a.y);
  tile[tr][tc4 + 2] = f2b(a.z); tile[tr][tc4 + 3] = f2b(a.w);
  __syncthreads();
  union { u16 u[4]; uint2 v; } pk;
  pk.u[0] = tile[tc4 + 0][tr]; pk.u[1] = tile[tc4 + 1][tr];
  pk.u[2] = tile[tc4 + 2][tr]; pk.u[3] = tile[tc4 + 3][tr];
  *(uint2*)&out[(size_t)(n0 + tr) * DIM + k0 + tc4] = pk.v;
}

// ---------------------------------------------------------------------------
// QKV GEMM bf16 MFMA: xa [4096][1024] x wt [3072][1024](=w^T) + bias.
// Q -> qbuf [bh][S][64] scaled by 0.125*log2e; K -> kbuf [bh][S][64];
// V -> vtbuf [bh][64][S] DIRECTLY TRANSPOSED (kills the vtrans kernel;
//   per (nb,mb) the 4 r-values are 4 consecutive s -> uint2 packed store).
// 128x128 tile, BK=64, 4 waves (2x2). XCD-swizzled 1D grid (768 = 8*96).
// ---------------------------------------------------------------------------
__global__ __launch_bounds__(256) void gemm_qkv_bf16(
    const u16* __restrict__ xa, const u16* __restrict__ wt,
    const float* __restrict__ bias,
    u16* __restrict__ qbuf, u16* __restrict__ kbuf, u16* __restrict__ vtbuf) {
  __shared__ __align__(16) u16 As[128 * 64];
  __shared__ __align__(16) u16 Bs[128 * 64];
  const int tid = threadIdx.x, w = tid >> 6, lane = tid & 63;
  const int l15 = lane & 15, l4 = lane >> 4;
  const int lin = blockIdx.x;
  const int swz = (lin & 7) * 96 + (lin >> 3);   // XCD chunk = 3 n-bands x 32 m
  const int m0 = (swz & 31) * 128, n0 = (swz >> 5) * 128;
  const int wm = (w >> 1) * 64, wn = (w & 1) * 64;

  f32x4 acc[4][4];
#pragma unroll
  for (int i = 0; i < 4; ++i)
#pragma unroll
    for (int j = 0; j < 4; ++j) acc[i][j] = zero4();

  for (int k0 = 0; k0 < DIM; k0 += 64) {
#pragma unroll
    for (int j = 0; j < 4; ++j) {
      const int rowX = (w * 4 + j) * 8 + (lane >> 3);
      const int kcol = k0 + (lane & 7) * 8;
      GLD_LDS16(&xa[(size_t)(m0 + rowX) * DIM + kcol], &As[(w * 4 + j) * 512]);
      GLD_LDS16(&wt[(size_t)(n0 + rowX) * DIM + kcol], &Bs[(w * 4 + j) * 512]);
    }
    asm volatile("s_waitcnt vmcnt(0)" ::: "memory");
    __syncthreads();
#pragma unroll
    for (int kc = 0; kc < 2; ++kc) {
      short8 af[4], bfr[4];
#pragma unroll
      for (int mb = 0; mb < 4; ++mb)
        af[mb] = *(const short8*)&As[(wm + mb * 16 + l15) * 64 + kc * 32 + l4 * 8];
#pragma unroll
      for (int nb = 0; nb < 4; ++nb)
        bfr[nb] = *(const short8*)&Bs[(wn + nb * 16 + l15) * 64 + kc * 32 + l4 * 8];
#pragma unroll
      for (int mb = 0; mb < 4; ++mb)
#pragma unroll
        for (int nb = 0; nb < 4; ++nb)
          acc[mb][nb] = __builtin_amdgcn_mfma_f32_16x16x32_bf16(
              af[mb], bfr[nb], acc[mb][nb], 0, 0, 0);
    }
    __syncthreads();
  }

  const int colb  = n0 + wn;
  const int which = colb >> 10;
  const int head  = (colb & 1023) >> 6;
  if (which == 2) {
    // V^T path: vt[bh][h][s], pack 4 consecutive s per store
#pragma unroll
    for (int nb = 0; nb < 4; ++nb) {
      const int col = colb + nb * 16 + l15;
      const float bv = bias[col];
      const int h = col & 63;
#pragma unroll
      for (int mb = 0; mb < 4; ++mb) {
        const int rowbase = m0 + wm + mb * 16 + l4 * 4;
        const int b = rowbase >> 11, s0 = rowbase & 2047;
        union { u16 u[4]; uint2 v; } pk;
#pragma unroll
        for (int r = 0; r < 4; ++r) pk.u[r] = f2b(acc[mb][nb][r] + bv);
        *(uint2*)&vtbuf[((size_t)((b * NHEADS + head) * 64 + h)) * SS + s0] = pk.v;
      }
    }
  } else {
    u16* __restrict__ dst = (which == 0) ? qbuf : kbuf;
    const float scale = (which == 0) ? QSCALE : 1.0f;
#pragma unroll
    for (int nb = 0; nb < 4; ++nb) {
      const int col = colb + nb * 16 + l15;
      const float bv = bias[col];
      const int h = col & 63;
#pragma unroll
      for (int mb = 0; mb < 4; ++mb)
#pragma unroll
        for (int r = 0; r < 4; ++r) {
          const int row = m0 + wm + mb * 16 + l4 * 4 + r;
          const int b = row >> 11, s = row & 2047;
          dst[((size_t)((b * NHEADS + head) * SS + s)) * 64 + h] =
              f2b((acc[mb][nb][r] + bv) * scale);
        }
    }
  }
}

// ---------------------------------------------------------------------------
// Flash attention bf16 MFMA: swapped operands + gld_lds double-buffer.
// Block = 256 thr / 4 waves; wave w owns q-rows qt*64+w*16+l15 (q = lane&15).
// S^T = mfma(K,Q); O^T = mfma(V,P).  K/V staged via global_load_lds with the
// XOR swizzle folded into the GLOBAL source chunk (linear LDS dest, rule #21).
// 2-phase pipeline: issue tile t+1 DMA, compute tile t, vmcnt(0)+barrier.
// exp2-domain softmax (Q pre-scaled); defer-max rescale (T13, THR=8).
// T5 setprio(1) around both MFMA clusters (attn-proven +4-7%, m191).
// __launch_bounds__(256,4): forbids the spill-for-occupancy heuristic (R3).
// ---------------------------------------------------------------------------
__global__ __launch_bounds__(256, 4) void attn_mfma(
    const u16* __restrict__ qbuf, const u16* __restrict__ kbuf,
    const u16* __restrict__ vtbuf, u16* __restrict__ aobuf) {
  __shared__ __align__(16) u16 Ks[2][64 * 64];
  __shared__ __align__(16) u16 Vs[2][64 * 64];
  __shared__ __align__(16) u16 Ps[4][16 * 64];
  const int tid = threadIdx.x, w = tid >> 6, lane = tid & 63;
  const int l15 = lane & 15, l4 = lane >> 4;
  const int lin = blockIdx.x;
  const int swz = (lin & 7) * 128 + (lin >> 3);  // XCD chunk = 4 bh x 32 qt
  const int bh = swz >> 5, qt = swz & 31;
  const int b = bh >> 4, head = bh & 15;

  const u16* __restrict__ qsrc  = qbuf + ((size_t)(bh * SS + qt * 64 + w * 16)) * 64;
  const u16* __restrict__ kbase = kbuf + (size_t)bh * SS * 64;
  const u16* __restrict__ vtb   = vtbuf + (size_t)bh * 64 * SS;

  short8 qf[2];
#pragma unroll
  for (int kc = 0; kc < 2; ++kc)
    qf[kc] = *(const short8*)&qsrc[l15 * 64 + kc * 32 + l4 * 8];

  const int srow8 = lane >> 3;           // 0..7  (== row & 7)
  const int schk  = (lane & 7) ^ srow8;  // swizzled source 16B-chunk

#define STAGE(t, bi)                                                          \
  {                                                                           \
    const int r0 = w * 16;                                                    \
    const u16* kp = kbase + ((size_t)((t) * 64 + r0 + srow8)) * 64 + schk * 8;\
    GLD_LDS16(kp,          &Ks[bi][r0 * 64]);                                 \
    GLD_LDS16(kp + 8 * 64, &Ks[bi][(r0 + 8) * 64]);                           \
    const u16* vp = vtb + (size_t)(r0 + srow8) * SS + (t) * 64 + schk * 8;    \
    GLD_LDS16(vp,          &Vs[bi][r0 * 64]);                                 \
    GLD_LDS16(vp + 8 * SS, &Vs[bi][(r0 + 8) * 64]);                           \
  }

  STAGE(0, 0);
  asm volatile("s_waitcnt vmcnt(0)" ::: "memory");
  __syncthreads();

  f32x4 acco[4];
#pragma unroll
  for (int i = 0; i < 4; ++i) acco[i] = zero4();
  float mrun = -1e30f, lrun = 0.f;

  for (int kt = 0; kt < SS / 64; ++kt) {
    const int cur = kt & 1;

    // issue next tile's DMA into the other buffer (flies under compute)
    if (kt + 1 < SS / 64) STAGE(kt + 1, 1 - cur);

    // S^T = mfma(K, Q): lane q=l15, keys nb*16 + l4*4 + r
    f32x4 sc[4];
#pragma unroll
    for (int i = 0; i < 4; ++i) sc[i] = zero4();
    __builtin_amdgcn_s_setprio(1);
#pragma unroll
    for (int kc = 0; kc < 2; ++kc)
#pragma unroll
      for (int nb = 0; nb < 4; ++nb) {
        const int key = nb * 16 + l15;
        const int cc = (kc * 4 + l4) ^ (l15 & 7);
        const short8 kf = *(const short8*)&Ks[cur][key * 64 + cc * 8];
        sc[nb] = __builtin_amdgcn_mfma_f32_16x16x32_bf16(kf, qf[kc], sc[nb], 0, 0, 0);
      }
    __builtin_amdgcn_s_setprio(0);

    // lane-scalar online softmax (exp2 domain)
    float tmax = sc[0][0];
#pragma unroll
    for (int nb = 0; nb < 4; ++nb)
#pragma unroll
      for (int r = 0; r < 4; ++r) tmax = fmaxf(tmax, sc[nb][r]);
    tmax = fmaxf(tmax, __shfl_xor(tmax, 16));
    tmax = fmaxf(tmax, __shfl_xor(tmax, 32));
    if (__ballot(tmax > mrun + 8.0f)) {   // defer-max: rescale only on real growth
      const float mnew = fmaxf(mrun, tmax);
      const float f = exp2f(mrun - mnew);
      mrun = mnew;
      lrun *= f;
#pragma unroll
      for (int nb = 0; nb < 4; ++nb)
#pragma unroll
        for (int r = 0; r < 4; ++r) acco[nb][r] *= f;
    }
    float p[4][4], rs = 0.f;
#pragma unroll
    for (int nb = 0; nb < 4; ++nb)
#pragma unroll
      for (int r = 0; r < 4; ++r) {
        p[nb][r] = exp2f(sc[nb][r] - mrun);
        rs += p[nb][r];
      }
    rs += __shfl_xor(rs, 16);
    rs += __shfl_xor(rs, 32);
    lrun += rs;

    // P -> LDS: 4 consecutive keys per write (swizzled b64)
#pragma unroll
    for (int nb = 0; nb < 4; ++nb) {
      union { u16 u[4]; uint2 v; } pk;
#pragma unroll
      for (int r = 0; r < 4; ++r) pk.u[r] = f2b(p[nb][r]);
      const int cc = (nb * 2 + (l4 >> 1)) ^ (l15 & 7);
      *(uint2*)&Ps[w][l15 * 64 + cc * 8 + (l4 & 1) * 4] = pk.v;
    }

    // O^T += mfma(V, P)
    __builtin_amdgcn_s_setprio(1);
#pragma unroll
    for (int kc = 0; kc < 2; ++kc) {
      const int ccp = (kc * 4 + l4) ^ (l15 & 7);
      const short8 pf = *(const short8*)&Ps[w][l15 * 64 + ccp * 8];
#pragma unroll
      for (int nb = 0; nb < 4; ++nb) {
        const int h = nb * 16 + l15;
        const int cv = (kc * 4 + l4) ^ (l15 & 7);
        const short8 vf = *(const short8*)&Vs[cur][h * 64 + cv * 8];
        acco[nb] = __builtin_amdgcn_mfma_f32_16x16x32_bf16(vf, pf, acco[nb], 0, 0, 0);
      }
    }
    __builtin_amdgcn_s_setprio(0);

    // prefetch for tile kt+1 must have landed before next iteration reads it
    asm volatile("s_waitcnt vmcnt(0)" ::: "memory");
    __syncthreads();
  }
#undef STAGE

  // epilogue: O[q=l15][h=nb*16+l4*4+r] / lrun -> ao [4096][1024] bf16
  const float inv = 1.f / lrun;
  const int s = qt * 64 + w * 16 + l15;
  u16* __restrict__ dst = aobuf + (size_t)(b * SS + s) * DIM + head * 64;
#pragma unroll
  for (int nb = 0; nb < 4; ++nb) {
    union { u16 u[4]; uint2 v; } pk;
#pragma unroll
    for (int r = 0; r < 4; ++r) pk.u[r] = f2b(acco[nb][r] * inv);
    *(uint2*)&dst[nb * 16 + l4 * 4] = pk.v;
  }
}

// ---------------------------------------------------------------------------
// Proj GEMM bf16 MFMA: ao [4096][1024] x wpt [1024][1024](=w^T) + bias -> fp32
// XCD-swizzled 1D grid (256 = 8*32).
// ---------------------------------------------------------------------------
__global__ __launch_bounds__(256) void gemm_proj_bf16(
    const u16* __restrict__ ao, const u16* __restrict__ wpt,
    const float* __restrict__ bias, float* __restrict__ out) {
  __shared__ __align__(16) u16 As[128 * 64];
  __shared__ __align__(16) u16 Bs[128 * 64];
  const int tid = threadIdx.x, w = tid >> 6, lane = tid & 63;
  const int l15 = lane & 15, l4 = lane >> 4;
  const int lin = blockIdx.x;
  const int swz = (lin & 7) * 32 + (lin >> 3);
  const int m0 = (swz & 31) * 128, n0 = (swz >> 5) * 128;
  const int wm = (w >> 1) * 64, wn = (w & 1) * 64;

  f32x4 acc[4][4];
#pragma unroll
  for (int i = 0; i < 4; ++i)
#pragma unroll
    for (int j = 0; j < 4; ++j) acc[i][j] = zero4();

  for (int k0 = 0; k0 < DIM; k0 += 64) {
#pragma unroll
    for (int j = 0; j < 4; ++j) {
      const int rowX = (w * 4 + j) * 8 + (lane >> 3);
      const int kcol = k0 + (lane & 7) * 8;
      GLD_LDS16(&ao[(size_t)(m0 + rowX) * DIM + kcol], &As[(w * 4 + j) * 512]);
      GLD_LDS16(&wpt[(size_t)(n0 + rowX) * DIM + kcol], &Bs[(w * 4 + j) * 512]);
    }
    asm volatile("s_waitcnt vmcnt(0)" ::: "memory");
    __syncthreads();
#pragma unroll
    for (int kc = 0; kc < 2; ++kc) {
      short8 af[4], bfr[4];
#pragma unroll
      for (int mb = 0; mb < 4; ++mb)
        af[mb] = *(const short8*)&As[(wm + mb * 16 + l15) * 64 + kc * 32 + l4 * 8];
#pragma unroll
      for (int nb = 0; nb < 4; ++nb)
        bfr[nb] = *(const short8*)&Bs[(wn + nb * 16 + l15) * 64 + kc * 32 + l4 * 8];
#pragma unroll
      for (int mb = 0; mb < 4; ++mb)
#pragma unroll
        for (int nb = 0; nb < 4; ++nb)
          acc[mb][nb] = __builtin_amdgcn_mfma_f32_16x16x32_bf16(
              af[mb], bfr[nb], acc[mb][nb], 0, 0, 0);
    }
    __syncthreads();
  }
#pragma unroll
  for (int nb = 0; nb < 4; ++nb) {
    const int col = n0 + wn + nb * 16 + l15;
    const float bv = bias[col];
#pragma unroll
    for (int mb = 0; mb < 4; ++mb)
#pragma unroll
      for (int r = 0; r < 4; ++r) {
        const int row = m0 + wm + mb * 16 + l4 * 4 + r;
        out[(size_t)row * DIM + col] = acc[mb][nb][r] + bv;
      }
  }
}

// ---------------------------------------------------------------------------
extern "C" void kernel_launch(void* const* d_in, const int* in_sizes, int n_in,
                              void* d_out, int out_size, void* d_ws, size_t ws_size,
                              hipStream_t stream) {
  const float* x      = (const float*)d_in[0];
  const float* w_qkv  = (const float*)d_in[1];
  const float* b_qkv  = (const float*)d_in[2];
  const float* w_proj = (const float*)d_in[3];
  const float* b_proj = (const float*)d_in[4];
  float* out = (float*)d_out;

  u16* ws = (u16*)d_ws;
  u16* x_bf    = ws;                               // 4096*1024
  u16* wqkv_t  = x_bf   + (size_t)MTOT * DIM;      // 3072*1024
  u16* wproj_t = wqkv_t + (size_t)3 * DIM * DIM;   // 1024*1024
  u16* qbuf    = wproj_t + (size_t)DIM * DIM;      // [bh][S][64]
  u16* kbuf    = qbuf + (size_t)MTOT * DIM;        // [bh][S][64]
  u16* vtbuf   = kbuf + (size_t)MTOT * DIM;        // [bh][64][S]
  u16* aobuf   = vtbuf + (size_t)MTOT * DIM;       // [4096][1024]

  prep_kernel<<<6144, 256, 0, stream>>>(x, w_qkv, w_proj, x_bf, wqkv_t, wproj_t);
  gemm_qkv_bf16<<<768, 256, 0, stream>>>(x_bf, wqkv_t, b_qkv, qbuf, kbuf, vtbuf);
  attn_mfma<<<1024, 256, 0, stream>>>(qbuf, kbuf, vtbuf, aobuf);
  gemm_proj_bf16<<<256, 256, 0, stream>>>(aobuf, wproj_t, b_proj, out);
}

// Round 7
// 225.442 us; speedup vs baseline: 1.3808x; 1.0293x over previous
//
#include <hip/hip_runtime.h>
#include <hip/hip_bf16.h>

#define DIM    1024
#define NHEADS 16
#define HDIM   64
#define BB     2
#define SS     2048
#define MTOT   (BB * SS)  // 4096

typedef unsigned short u16;
typedef __attribute__((ext_vector_type(8))) short short8;   // 8 bf16 = 4 VGPR (MFMA A/B frag)
typedef __attribute__((ext_vector_type(4))) float f32x4;    // MFMA C/D frag

__device__ inline u16 f2b(float f) {
  __hip_bfloat16 h = __float2bfloat16(f);
  return *reinterpret_cast<u16*>(&h);
}
__device__ inline f32x4 zero4() { f32x4 v = {0.f, 0.f, 0.f, 0.f}; return v; }

// async global->LDS, 16B per lane; LDS dest = wave-uniform base + lane*16
#define GLD_LDS16(GP, LP)                                                   \
  __builtin_amdgcn_global_load_lds(                                         \
      (const __attribute__((address_space(1))) unsigned int*)               \
          (unsigned long long)(const void*)(GP),                            \
      (__attribute__((address_space(3))) unsigned int*)                     \
          (unsigned int)(unsigned long long)(const void*)(LP),              \
      16, 0, 0)

#define QSCALE 0.18033688011112042f  // 0.125 * log2(e): exp2 domain, exact softmax

// ---------------------------------------------------------------------------
// Fused prep: [0,2048)   cast x fp32->bf16 (8 elems/thread)
//             [2048,5120) transpose+cast w_qkv [1024][3072] -> [3072][1024]
//             [5120,6144) transpose+cast w_proj [1024][1024] -> [1024][1024]
// ---------------------------------------------------------------------------
__global__ __launch_bounds__(256) void prep_kernel(
    const float* __restrict__ x, const float* __restrict__ wq,
    const float* __restrict__ wp,
    u16* __restrict__ x_bf, u16* __restrict__ wqt, u16* __restrict__ wpt) {
  __shared__ u16 tile[32][36];
  const int t   = threadIdx.x;
  const int blk = blockIdx.x;
  if (blk < 2048) {
    const int i = blk * 256 + t;
    const float4 a = ((const float4*)x)[i * 2];
    const float4 b = ((const float4*)x)[i * 2 + 1];
    union { u16 u[8]; uint4 v; } r;
    r.u[0] = f2b(a.x); r.u[1] = f2b(a.y); r.u[2] = f2b(a.z); r.u[3] = f2b(a.w);
    r.u[4] = f2b(b.x); r.u[5] = f2b(b.y); r.u[6] = f2b(b.z); r.u[7] = f2b(b.w);
    ((uint4*)x_bf)[i] = r.v;
    return;
  }
  const float* __restrict__ in;
  u16* __restrict__ out;
  int N, n0, k0;
  if (blk < 5120) {
    const int b2 = blk - 2048;
    in = wq; out = wqt; N = 3072;
    n0 = (b2 % 96) * 32; k0 = (b2 / 96) * 32;
  } else {
    const int b2 = blk - 5120;
    in = wp; out = wpt; N = 1024;
    n0 = (b2 & 31) * 32; k0 = (b2 >> 5) * 32;
  }
  const int tr = t >> 3, tc4 = (t & 7) * 4;
  const float4 a = *(const float4*)&in[(size_t)(k0 + tr) * N + n0 + tc4];
  tile[tr][tc4 + 0] = f2b(a.x); tile[tr][tc4 + 1] = f2b(a.y);
  tile[tr][tc4 + 2] = f2b(a.z); tile[tr][tc4 + 3] = f2b(a.w);
  __syncthreads();
  union { u16 u[4]; uint2 v; } pk;
  pk.u[0] = tile[tc4 + 0][tr]; pk.u[1] = tile[tc4 + 1][tr];
  pk.u[2] = tile[tc4 + 2][tr]; pk.u[3] = tile[tc4 + 3][tr];
  *(uint2*)&out[(size_t)(n0 + tr) * DIM + k0 + tc4] = pk.v;
}

// ---------------------------------------------------------------------------
// QKV GEMM bf16 MFMA: xa [4096][1024] x wt [3072][1024](=w^T) + bias.
// Q -> qbuf [bh][S][64] scaled; K -> kbuf [bh][S][64]; V -> vtbuf [bh][64][S]
// directly transposed. 128x128 tile, BK=64, 4 waves. XCD-swizzled grid (768).
// ---------------------------------------------------------------------------
__global__ __launch_bounds__(256) void gemm_qkv_bf16(
    const u16* __restrict__ xa, const u16* __restrict__ wt,
    const float* __restrict__ bias,
    u16* __restrict__ qbuf, u16* __restrict__ kbuf, u16* __restrict__ vtbuf) {
  __shared__ __align__(16) u16 As[128 * 64];
  __shared__ __align__(16) u16 Bs[128 * 64];
  const int tid = threadIdx.x, w = tid >> 6, lane = tid & 63;
  const int l15 = lane & 15, l4 = lane >> 4;
  const int lin = blockIdx.x;
  const int swz = (lin & 7) * 96 + (lin >> 3);   // XCD chunk = 3 n-bands x 32 m
  const int m0 = (swz & 31) * 128, n0 = (swz >> 5) * 128;
  const int wm = (w >> 1) * 64, wn = (w & 1) * 64;

  f32x4 acc[4][4];
#pragma unroll
  for (int i = 0; i < 4; ++i)
#pragma unroll
    for (int j = 0; j < 4; ++j) acc[i][j] = zero4();

  for (int k0 = 0; k0 < DIM; k0 += 64) {
#pragma unroll
    for (int j = 0; j < 4; ++j) {
      const int rowX = (w * 4 + j) * 8 + (lane >> 3);
      const int kcol = k0 + (lane & 7) * 8;
      GLD_LDS16(&xa[(size_t)(m0 + rowX) * DIM + kcol], &As[(w * 4 + j) * 512]);
      GLD_LDS16(&wt[(size_t)(n0 + rowX) * DIM + kcol], &Bs[(w * 4 + j) * 512]);
    }
    asm volatile("s_waitcnt vmcnt(0)" ::: "memory");
    __syncthreads();
#pragma unroll
    for (int kc = 0; kc < 2; ++kc) {
      short8 af[4], bfr[4];
#pragma unroll
      for (int mb = 0; mb < 4; ++mb)
        af[mb] = *(const short8*)&As[(wm + mb * 16 + l15) * 64 + kc * 32 + l4 * 8];
#pragma unroll
      for (int nb = 0; nb < 4; ++nb)
        bfr[nb] = *(const short8*)&Bs[(wn + nb * 16 + l15) * 64 + kc * 32 + l4 * 8];
#pragma unroll
      for (int mb = 0; mb < 4; ++mb)
#pragma unroll
        for (int nb = 0; nb < 4; ++nb)
          acc[mb][nb] = __builtin_amdgcn_mfma_f32_16x16x32_bf16(
              af[mb], bfr[nb], acc[mb][nb], 0, 0, 0);
    }
    __syncthreads();
  }

  const int colb  = n0 + wn;
  const int which = colb >> 10;
  const int head  = (colb & 1023) >> 6;
  if (which == 2) {
    // V^T path: vt[bh][h][s], pack 4 consecutive s per store
#pragma unroll
    for (int nb = 0; nb < 4; ++nb) {
      const int col = colb + nb * 16 + l15;
      const float bv = bias[col];
      const int h = col & 63;
#pragma unroll
      for (int mb = 0; mb < 4; ++mb) {
        const int rowbase = m0 + wm + mb * 16 + l4 * 4;
        const int b = rowbase >> 11, s0 = rowbase & 2047;
        union { u16 u[4]; uint2 v; } pk;
#pragma unroll
        for (int r = 0; r < 4; ++r) pk.u[r] = f2b(acc[mb][nb][r] + bv);
        *(uint2*)&vtbuf[((size_t)((b * NHEADS + head) * 64 + h)) * SS + s0] = pk.v;
      }
    }
  } else {
    u16* __restrict__ dst = (which == 0) ? qbuf : kbuf;
    const float scale = (which == 0) ? QSCALE : 1.0f;
#pragma unroll
    for (int nb = 0; nb < 4; ++nb) {
      const int col = colb + nb * 16 + l15;
      const float bv = bias[col];
      const int h = col & 63;
#pragma unroll
      for (int mb = 0; mb < 4; ++mb)
#pragma unroll
        for (int r = 0; r < 4; ++r) {
          const int row = m0 + wm + mb * 16 + l4 * 4 + r;
          const int b = row >> 11, s = row & 2047;
          dst[((size_t)((b * NHEADS + head) * SS + s)) * 64 + h] =
              f2b((acc[mb][nb][r] + bv) * scale);
        }
    }
  }
}

// ---------------------------------------------------------------------------
// Flash attention bf16 MFMA v4: QBLK=128 (8 waves, 512 thr), KVBLK=64.
// Wave w owns q-rows qt*128 + w*16 + l15 (q = lane&15).
// S^T = mfma(K,Q); O^T = mfma(V,P).  K/V staged via global_load_lds, XOR
// swizzle folded into GLOBAL source chunk (linear LDS dest, rule #21).
// One K/V tile serves 128 q-rows: 1 gld_lds per thread per tile (was 2 at
// QBLK=64) -> staging issue work and K/V re-stage count halve.
// 2-phase pipeline; exp2 softmax; defer-max (THR=8).
// LDS 48KB -> 3 blocks/CU cap; grid 512 = 2/CU resident, 4 waves/SIMD.
// ---------------------------------------------------------------------------
__global__ __launch_bounds__(512, 4) void attn_mfma(
    const u16* __restrict__ qbuf, const u16* __restrict__ kbuf,
    const u16* __restrict__ vtbuf, u16* __restrict__ aobuf) {
  __shared__ __align__(16) u16 Ks[2][64 * 64];
  __shared__ __align__(16) u16 Vs[2][64 * 64];
  __shared__ __align__(16) u16 Ps[8][16 * 64];
  const int tid = threadIdx.x, w = tid >> 6, lane = tid & 63;
  const int l15 = lane & 15, l4 = lane >> 4;
  const int lin = blockIdx.x;
  const int swz = (lin & 7) * 64 + (lin >> 3);   // XCD chunk = 4 bh x 16 qt
  const int bh = swz >> 4, qt = swz & 15;
  const int b = bh >> 4, head = bh & 15;

  const u16* __restrict__ qsrc  = qbuf + ((size_t)(bh * SS + qt * 128 + w * 16)) * 64;
  const u16* __restrict__ kbase = kbuf + (size_t)bh * SS * 64;
  const u16* __restrict__ vtb   = vtbuf + (size_t)bh * 64 * SS;

  short8 qf[2];
#pragma unroll
  for (int kc = 0; kc < 2; ++kc)
    qf[kc] = *(const short8*)&qsrc[l15 * 64 + kc * 32 + l4 * 8];

  // staging: wave w covers rows [w*8, w*8+8) of the 64-row K and Vt tiles.
  // lane l: row = w*8 + (l>>3), source chunk (l&7) ^ (row&7)  (inverse swizzle)
  const int srow  = w * 8 + (lane >> 3);
  const int schk  = (lane & 7) ^ (srow & 7);

#define STAGE(t, bi)                                                          \
  {                                                                           \
    GLD_LDS16(kbase + ((size_t)((t) * 64 + srow)) * 64 + schk * 8,            \
              &Ks[bi][w * 8 * 64]);                                           \
    GLD_LDS16(vtb + (size_t)srow * SS + (t) * 64 + schk * 8,                  \
              &Vs[bi][w * 8 * 64]);                                           \
  }

  STAGE(0, 0);
  asm volatile("s_waitcnt vmcnt(0)" ::: "memory");
  __syncthreads();

  f32x4 acco[4];
#pragma unroll
  for (int i = 0; i < 4; ++i) acco[i] = zero4();
  float mrun = -1e30f, lrun = 0.f;

  for (int kt = 0; kt < SS / 64; ++kt) {
    const int cur = kt & 1;

    // issue next tile's DMA into the other buffer (flies under compute)
    if (kt + 1 < SS / 64) STAGE(kt + 1, 1 - cur);

    // S^T = mfma(K, Q): lane q=l15, keys nb*16 + l4*4 + r
    f32x4 sc[4];
#pragma unroll
    for (int i = 0; i < 4; ++i) sc[i] = zero4();
    __builtin_amdgcn_s_setprio(1);
#pragma unroll
    for (int kc = 0; kc < 2; ++kc)
#pragma unroll
      for (int nb = 0; nb < 4; ++nb) {
        const int key = nb * 16 + l15;
        const int cc = (kc * 4 + l4) ^ (l15 & 7);
        const short8 kf = *(const short8*)&Ks[cur][key * 64 + cc * 8];
        sc[nb] = __builtin_amdgcn_mfma_f32_16x16x32_bf16(kf, qf[kc], sc[nb], 0, 0, 0);
      }
    __builtin_amdgcn_s_setprio(0);

    // lane-scalar online softmax (exp2 domain)
    float tmax = sc[0][0];
#pragma unroll
    for (int nb = 0; nb < 4; ++nb)
#pragma unroll
      for (int r = 0; r < 4; ++r) tmax = fmaxf(tmax, sc[nb][r]);
    tmax = fmaxf(tmax, __shfl_xor(tmax, 16));
    tmax = fmaxf(tmax, __shfl_xor(tmax, 32));
    if (__ballot(tmax > mrun + 8.0f)) {   // defer-max: rescale only on real growth
      const float mnew = fmaxf(mrun, tmax);
      const float f = exp2f(mrun - mnew);
      mrun = mnew;
      lrun *= f;
#pragma unroll
      for (int nb = 0; nb < 4; ++nb)
#pragma unroll
        for (int r = 0; r < 4; ++r) acco[nb][r] *= f;
    }
    float p[4][4], rs = 0.f;
#pragma unroll
    for (int nb = 0; nb < 4; ++nb)
#pragma unroll
      for (int r = 0; r < 4; ++r) {
        p[nb][r] = exp2f(sc[nb][r] - mrun);
        rs += p[nb][r];
      }
    rs += __shfl_xor(rs, 16);
    rs += __shfl_xor(rs, 32);
    lrun += rs;

    // P -> LDS: 4 consecutive keys per write (swizzled b64)
#pragma unroll
    for (int nb = 0; nb < 4; ++nb) {
      union { u16 u[4]; uint2 v; } pk;
#pragma unroll
      for (int r = 0; r < 4; ++r) pk.u[r] = f2b(p[nb][r]);
      const int cc = (nb * 2 + (l4 >> 1)) ^ (l15 & 7);
      *(uint2*)&Ps[w][l15 * 64 + cc * 8 + (l4 & 1) * 4] = pk.v;
    }

    // O^T += mfma(V, P)
    __builtin_amdgcn_s_setprio(1);
#pragma unroll
    for (int kc = 0; kc < 2; ++kc) {
      const int ccp = (kc * 4 + l4) ^ (l15 & 7);
      const short8 pf = *(const short8*)&Ps[w][l15 * 64 + ccp * 8];
#pragma unroll
      for (int nb = 0; nb < 4; ++nb) {
        const int h = nb * 16 + l15;
        const int cv = (kc * 4 + l4) ^ (l15 & 7);
        const short8 vf = *(const short8*)&Vs[cur][h * 64 + cv * 8];
        acco[nb] = __builtin_amdgcn_mfma_f32_16x16x32_bf16(vf, pf, acco[nb], 0, 0, 0);
      }
    }
    __builtin_amdgcn_s_setprio(0);

    // prefetch for tile kt+1 must have landed before next iteration reads it
    asm volatile("s_waitcnt vmcnt(0)" ::: "memory");
    __syncthreads();
  }
#undef STAGE

  // epilogue: O[q=l15][h=nb*16+l4*4+r] / lrun -> ao [4096][1024] bf16
  const float inv = 1.f / lrun;
  const int s = qt * 128 + w * 16 + l15;
  u16* __restrict__ dst = aobuf + (size_t)(b * SS + s) * DIM + head * 64;
#pragma unroll
  for (int nb = 0; nb < 4; ++nb) {
    union { u16 u[4]; uint2 v; } pk;
#pragma unroll
    for (int r = 0; r < 4; ++r) pk.u[r] = f2b(acco[nb][r] * inv);
    *(uint2*)&dst[nb * 16 + l4 * 4] = pk.v;
  }
}

// ---------------------------------------------------------------------------
// Proj GEMM bf16 MFMA: ao [4096][1024] x wpt [1024][1024](=w^T) + bias -> fp32
// 128x64 tile, 4 waves (2x2, each 64x32) -> grid 512 = 2 blocks/CU (was 256
// = 1/CU: stage-wait fully exposed with no co-resident block to hide it).
// XCD-swizzled 1D grid (512 = 8*64).
// ---------------------------------------------------------------------------
__global__ __launch_bounds__(256) void gemm_proj_bf16(
    const u16* __restrict__ ao, const u16* __restrict__ wpt,
    const float* __restrict__ bias, float* __restrict__ out) {
  __shared__ __align__(16) u16 As[128 * 64];
  __shared__ __align__(16) u16 Bs[64 * 64];
  const int tid = threadIdx.x, w = tid >> 6, lane = tid & 63;
  const int l15 = lane & 15, l4 = lane >> 4;
  const int lin = blockIdx.x;
  const int swz = (lin & 7) * 64 + (lin >> 3);   // XCD chunk = 2 n-bands x 32 m
  const int m0 = (swz & 31) * 128, n0 = (swz >> 5) * 64;
  const int wm = (w >> 1) * 64, wn = (w & 1) * 32;

  f32x4 acc[4][2];
#pragma unroll
  for (int i = 0; i < 4; ++i)
#pragma unroll
    for (int j = 0; j < 2; ++j) acc[i][j] = zero4();

  for (int k0 = 0; k0 < DIM; k0 += 64) {
#pragma unroll
    for (int j = 0; j < 4; ++j) {
      const int rowA = (w * 4 + j) * 8 + (lane >> 3);
      GLD_LDS16(&ao[(size_t)(m0 + rowA) * DIM + k0 + (lane & 7) * 8],
                &As[(w * 4 + j) * 512]);
    }
#pragma unroll
    for (int j = 0; j < 2; ++j) {
      const int rowB = (w * 2 + j) * 8 + (lane >> 3);
      GLD_LDS16(&wpt[(size_t)(n0 + rowB) * DIM + k0 + (lane & 7) * 8],
                &Bs[(w * 2 + j) * 512]);
    }
    asm volatile("s_waitcnt vmcnt(0)" ::: "memory");
    __syncthreads();
#pragma unroll
    for (int kc = 0; kc < 2; ++kc) {
      short8 af[4], bfr[2];
#pragma unroll
      for (int mb = 0; mb < 4; ++mb)
        af[mb] = *(const short8*)&As[(wm + mb * 16 + l15) * 64 + kc * 32 + l4 * 8];
#pragma unroll
      for (int nb = 0; nb < 2; ++nb)
        bfr[nb] = *(const short8*)&Bs[(wn + nb * 16 + l15) * 64 + kc * 32 + l4 * 8];
#pragma unroll
      for (int mb = 0; mb < 4; ++mb)
#pragma unroll
        for (int nb = 0; nb < 2; ++nb)
          acc[mb][nb] = __builtin_amdgcn_mfma_f32_16x16x32_bf16(
              af[mb], bfr[nb], acc[mb][nb], 0, 0, 0);
    }
    __syncthreads();
  }
#pragma unroll
  for (int nb = 0; nb < 2; ++nb) {
    const int col = n0 + wn + nb * 16 + l15;
    const float bv = bias[col];
#pragma unroll
    for (int mb = 0; mb < 4; ++mb)
#pragma unroll
      for (int r = 0; r < 4; ++r) {
        const int row = m0 + wm + mb * 16 + l4 * 4 + r;
        out[(size_t)row * DIM + col] = acc[mb][nb][r] + bv;
      }
  }
}

// ---------------------------------------------------------------------------
extern "C" void kernel_launch(void* const* d_in, const int* in_sizes, int n_in,
                              void* d_out, int out_size, void* d_ws, size_t ws_size,
                              hipStream_t stream) {
  const float* x      = (const float*)d_in[0];
  const float* w_qkv  = (const float*)d_in[1];
  const float* b_qkv  = (const float*)d_in[2];
  const float* w_proj = (const float*)d_in[3];
  const float* b_proj = (const float*)d_in[4];
  float* out = (float*)d_out;

  u16* ws = (u16*)d_ws;
  u16* x_bf    = ws;                               // 4096*1024
  u16* wqkv_t  = x_bf   + (size_t)MTOT * DIM;      // 3072*1024
  u16* wproj_t = wqkv_t + (size_t)3 * DIM * DIM;   // 1024*1024
  u16* qbuf    = wproj_t + (size_t)DIM * DIM;      // [bh][S][64]
  u16* kbuf    = qbuf + (size_t)MTOT * DIM;        // [bh][S][64]
  u16* vtbuf   = kbuf + (size_t)MTOT * DIM;        // [bh][64][S]
  u16* aobuf   = vtbuf + (size_t)MTOT * DIM;       // [4096][1024]

  prep_kernel<<<6144, 256, 0, stream>>>(x, w_qkv, w_proj, x_bf, wqkv_t, wproj_t);
  gemm_qkv_bf16<<<768, 256, 0, stream>>>(x_bf, wqkv_t, b_qkv, qbuf, kbuf, vtbuf);
  attn_mfma<<<512, 512, 0, stream>>>(qbuf, kbuf, vtbuf, aobuf);
  gemm_proj_bf16<<<512, 256, 0, stream>>>(aobuf, wproj_t, b_proj, out);
}

// Round 8
// 223.815 us; speedup vs baseline: 1.3909x; 1.0073x over previous
//
#include <hip/hip_runtime.h>
#include <hip/hip_bf16.h>

#define DIM    1024
#define NHEADS 16
#define HDIM   64
#define BB     2
#define SS     2048
#define MTOT   (BB * SS)  // 4096

typedef unsigned short u16;
typedef __attribute__((ext_vector_type(8))) short short8;   // 8 bf16 = 4 VGPR (MFMA A/B frag)
typedef __attribute__((ext_vector_type(4))) float f32x4;    // MFMA C/D frag

__device__ inline u16 f2b(float f) {
  __hip_bfloat16 h = __float2bfloat16(f);
  return *reinterpret_cast<u16*>(&h);
}
__device__ inline f32x4 zero4() { f32x4 v = {0.f, 0.f, 0.f, 0.f}; return v; }

// async global->LDS, 16B per lane; LDS dest = wave-uniform base + lane*16
#define GLD_LDS16(GP, LP)                                                   \
  __builtin_amdgcn_global_load_lds(                                         \
      (const __attribute__((address_space(1))) unsigned int*)               \
          (unsigned long long)(const void*)(GP),                            \
      (__attribute__((address_space(3))) unsigned int*)                     \
          (unsigned int)(unsigned long long)(const void*)(LP),              \
      16, 0, 0)

#define QSCALE 0.18033688011112042f  // 0.125 * log2(e): exp2 domain, exact softmax

// ---------------------------------------------------------------------------
// Fused prep: [0,2048)   cast x fp32->bf16 (8 elems/thread)
//             [2048,5120) transpose+cast w_qkv [1024][3072] -> [3072][1024]
//             [5120,6144) transpose+cast w_proj [1024][1024] -> [1024][1024]
// ---------------------------------------------------------------------------
__global__ __launch_bounds__(256) void prep_kernel(
    const float* __restrict__ x, const float* __restrict__ wq,
    const float* __restrict__ wp,
    u16* __restrict__ x_bf, u16* __restrict__ wqt, u16* __restrict__ wpt) {
  __shared__ u16 tile[32][36];
  const int t   = threadIdx.x;
  const int blk = blockIdx.x;
  if (blk < 2048) {
    const int i = blk * 256 + t;
    const float4 a = ((const float4*)x)[i * 2];
    const float4 b = ((const float4*)x)[i * 2 + 1];
    union { u16 u[8]; uint4 v; } r;
    r.u[0] = f2b(a.x); r.u[1] = f2b(a.y); r.u[2] = f2b(a.z); r.u[3] = f2b(a.w);
    r.u[4] = f2b(b.x); r.u[5] = f2b(b.y); r.u[6] = f2b(b.z); r.u[7] = f2b(b.w);
    ((uint4*)x_bf)[i] = r.v;
    return;
  }
  const float* __restrict__ in;
  u16* __restrict__ out;
  int N, n0, k0;
  if (blk < 5120) {
    const int b2 = blk - 2048;
    in = wq; out = wqt; N = 3072;
    n0 = (b2 % 96) * 32; k0 = (b2 / 96) * 32;
  } else {
    const int b2 = blk - 5120;
    in = wp; out = wpt; N = 1024;
    n0 = (b2 & 31) * 32; k0 = (b2 >> 5) * 32;
  }
  const int tr = t >> 3, tc4 = (t & 7) * 4;
  const float4 a = *(const float4*)&in[(size_t)(k0 + tr) * N + n0 + tc4];
  tile[tr][tc4 + 0] = f2b(a.x); tile[tr][tc4 + 1] = f2b(a.y);
  tile[tr][tc4 + 2] = f2b(a.z); tile[tr][tc4 + 3] = f2b(a.w);
  __syncthreads();
  union { u16 u[4]; uint2 v; } pk;
  pk.u[0] = tile[tc4 + 0][tr]; pk.u[1] = tile[tc4 + 1][tr];
  pk.u[2] = tile[tc4 + 2][tr]; pk.u[3] = tile[tc4 + 3][tr];
  *(uint2*)&out[(size_t)(n0 + tr) * DIM + k0 + tc4] = pk.v;
}

// ---------------------------------------------------------------------------
// QKV GEMM bf16 MFMA: xa [4096][1024] x wt [3072][1024](=w^T) + bias.
// Q -> qbuf [bh][S][64] scaled; K -> kbuf [bh][S][64]; V -> vtbuf [bh][64][S].
// V^T epilogue goes through swizzled wave-private LDS (reusing As/Bs) so the
// global stores are coalesced 128B dwordx4 (the old scattered uint2 stores hit
// 16 cachelines/instr = ~8x write amplification).
// 128x128 tile, BK=64, 4 waves. XCD-swizzled grid (768).
// ---------------------------------------------------------------------------
__global__ __launch_bounds__(256) void gemm_qkv_bf16(
    const u16* __restrict__ xa, const u16* __restrict__ wt,
    const float* __restrict__ bias,
    u16* __restrict__ qbuf, u16* __restrict__ kbuf, u16* __restrict__ vtbuf) {
  __shared__ __align__(16) u16 As[128 * 64];
  __shared__ __align__(16) u16 Bs[128 * 64];
  const int tid = threadIdx.x, w = tid >> 6, lane = tid & 63;
  const int l15 = lane & 15, l4 = lane >> 4;
  const int lin = blockIdx.x;
  const int swz = (lin & 7) * 96 + (lin >> 3);   // XCD chunk = 3 n-bands x 32 m
  const int m0 = (swz & 31) * 128, n0 = (swz >> 5) * 128;
  const int wm = (w >> 1) * 64, wn = (w & 1) * 64;

  f32x4 acc[4][4];
#pragma unroll
  for (int i = 0; i < 4; ++i)
#pragma unroll
    for (int j = 0; j < 4; ++j) acc[i][j] = zero4();

  for (int k0 = 0; k0 < DIM; k0 += 64) {
#pragma unroll
    for (int j = 0; j < 4; ++j) {
      const int rowX = (w * 4 + j) * 8 + (lane >> 3);
      const int kcol = k0 + (lane & 7) * 8;
      GLD_LDS16(&xa[(size_t)(m0 + rowX) * DIM + kcol], &As[(w * 4 + j) * 512]);
      GLD_LDS16(&wt[(size_t)(n0 + rowX) * DIM + kcol], &Bs[(w * 4 + j) * 512]);
    }
    asm volatile("s_waitcnt vmcnt(0)" ::: "memory");
    __syncthreads();
#pragma unroll
    for (int kc = 0; kc < 2; ++kc) {
      short8 af[4], bfr[4];
#pragma unroll
      for (int mb = 0; mb < 4; ++mb)
        af[mb] = *(const short8*)&As[(wm + mb * 16 + l15) * 64 + kc * 32 + l4 * 8];
#pragma unroll
      for (int nb = 0; nb < 4; ++nb)
        bfr[nb] = *(const short8*)&Bs[(wn + nb * 16 + l15) * 64 + kc * 32 + l4 * 8];
#pragma unroll
      for (int mb = 0; mb < 4; ++mb)
#pragma unroll
        for (int nb = 0; nb < 4; ++nb)
          acc[mb][nb] = __builtin_amdgcn_mfma_f32_16x16x32_bf16(
              af[mb], bfr[nb], acc[mb][nb], 0, 0, 0);
    }
    __syncthreads();
  }

  const int colb  = n0 + wn;
  const int which = colb >> 10;
  const int head  = (colb & 1023) >> 6;
  if (which == 2) {
    // V^T path via LDS repack. Wave-private 64x64 u16 region in As/Bs
    // (free after the loop's final barrier). 16B-chunk XOR swizzle
    // (chunk ^= h&7) keeps both ds_write_b64 and ds_read_b128 conflict-free.
    u16* __restrict__ wl = ((w < 2) ? As : Bs) + (w & 1) * 4096;
    const int rowbase = m0 + wm;                 // 64-aligned
    const int bidx = rowbase >> 11, sbase = rowbase & 2047;
    float bv[4];
#pragma unroll
    for (int nb = 0; nb < 4; ++nb) bv[nb] = bias[colb + nb * 16 + l15];
#pragma unroll
    for (int nb = 0; nb < 4; ++nb) {
      const int h = nb * 16 + l15;
#pragma unroll
      for (int mb = 0; mb < 4; ++mb) {
        union { u16 u[4]; uint2 v; } pk;
#pragma unroll
        for (int r = 0; r < 4; ++r) pk.u[r] = f2b(acc[mb][nb][r] + bv[nb]);
        const int csw = (mb * 2 + (l4 >> 1)) ^ (l15 & 7);
        *(uint2*)&wl[h * 64 + csw * 8 + (l4 & 1) * 4] = pk.v;
      }
    }
    // wave-private: program order + compiler lgkmcnt suffice (no barrier)
#pragma unroll
    for (int p = 0; p < 8; ++p) {
      const int h = (lane >> 3) + p * 8;
      const int csw = (lane & 7) ^ (h & 7);
      const uint4 d = *(const uint4*)&wl[h * 64 + csw * 8];
      *(uint4*)&vtbuf[((size_t)((bidx * NHEADS + head) * 64 + h)) * SS +
                      sbase + (lane & 7) * 8] = d;
    }
  } else {
    u16* __restrict__ dst = (which == 0) ? qbuf : kbuf;
    const float scale = (which == 0) ? QSCALE : 1.0f;
#pragma unroll
    for (int nb = 0; nb < 4; ++nb) {
      const int col = colb + nb * 16 + l15;
      const float bv = bias[col];
      const int h = col & 63;
#pragma unroll
      for (int mb = 0; mb < 4; ++mb)
#pragma unroll
        for (int r = 0; r < 4; ++r) {
          const int row = m0 + wm + mb * 16 + l4 * 4 + r;
          const int b = row >> 11, s = row & 2047;
          dst[((size_t)((b * NHEADS + head) * SS + s)) * 64 + h] =
              f2b((acc[mb][nb][r] + bv) * scale);
        }
    }
  }
}

// ---------------------------------------------------------------------------
// Flash attention bf16 MFMA v5: T15 double-pipeline (QK^T(t+1) on the MFMA
// pipe overlaps softmax(t) on the VALU — independent register streams;
// attn was VALU-bound: VALUBusy 59% vs MfmaUtil 19%).
// QBLK=128 (8 waves, 512 thr), KVBLK=64; S^T=mfma(K,Q), O^T=mfma(V,P).
// K double-buffered, V TRIPLE-buffered (PV(t) reads V[t] while t+2 stages).
// Unrolled by 2 with named scA/scB (rule #20: no runtime-indexed reg state).
// gld_lds staging with source-side XOR swizzle (rule #21); 1 vmcnt0+barrier
// per tile (unchanged). exp2 softmax; defer-max THR=8; max3 tmax tree (T17).
// ---------------------------------------------------------------------------
__global__ __launch_bounds__(512, 4) void attn_mfma(
    const u16* __restrict__ qbuf, const u16* __restrict__ kbuf,
    const u16* __restrict__ vtbuf, u16* __restrict__ aobuf) {
  __shared__ __align__(16) u16 Ks[2][64 * 64];
  __shared__ __align__(16) u16 Vs[3 * 64 * 64];
  __shared__ __align__(16) u16 Ps[8][16 * 64];
  const int tid = threadIdx.x, w = tid >> 6, lane = tid & 63;
  const int l15 = lane & 15, l4 = lane >> 4;
  const int lin = blockIdx.x;
  const int swz = (lin & 7) * 64 + (lin >> 3);   // XCD chunk = 4 bh x 16 qt
  const int bh = swz >> 4, qt = swz & 15;
  const int b = bh >> 4, head = bh & 15;

  const u16* __restrict__ qsrc  = qbuf + ((size_t)(bh * SS + qt * 128 + w * 16)) * 64;
  const u16* __restrict__ kbase = kbuf + (size_t)bh * SS * 64;
  const u16* __restrict__ vtb   = vtbuf + (size_t)bh * 64 * SS;

  short8 qf[2];
#pragma unroll
  for (int kc = 0; kc < 2; ++kc)
    qf[kc] = *(const short8*)&qsrc[l15 * 64 + kc * 32 + l4 * 8];

  const int srow  = w * 8 + (lane >> 3);
  const int schk  = (lane & 7) ^ (srow & 7);

#define STAGEK(t, bi)                                                         \
  GLD_LDS16(kbase + ((size_t)((t) * 64 + srow)) * 64 + schk * 8,              \
            &Ks[bi][w * 8 * 64]);
#define STAGEV(t, vi)                                                         \
  GLD_LDS16(vtb + (size_t)srow * SS + (t) * 64 + schk * 8,                    \
            &Vs[(vi) * 4096 + w * 8 * 64]);

#define QKT(KB, sc)                                                           \
  {                                                                           \
    _Pragma("unroll") for (int i = 0; i < 4; ++i) sc[i] = zero4();            \
    __builtin_amdgcn_s_setprio(1);                                            \
    _Pragma("unroll") for (int kc = 0; kc < 2; ++kc)                          \
      _Pragma("unroll") for (int nb = 0; nb < 4; ++nb) {                      \
        const int key = nb * 16 + l15;                                        \
        const int cc = (kc * 4 + l4) ^ (l15 & 7);                             \
        const short8 kf = *(const short8*)&(KB)[key * 64 + cc * 8];           \
        sc[nb] = __builtin_amdgcn_mfma_f32_16x16x32_bf16(kf, qf[kc], sc[nb],  \
                                                          0, 0, 0);           \
      }                                                                       \
    __builtin_amdgcn_s_setprio(0);                                            \
  }

#define SOFTMAX_P(sc)                                                         \
  {                                                                           \
    float t0 = fmaxf(fmaxf(sc[0][0], sc[0][1]), sc[0][2]);                    \
    t0 = fmaxf(fmaxf(t0, sc[0][3]), sc[1][0]);                                \
    t0 = fmaxf(fmaxf(t0, sc[1][1]), sc[1][2]);                                \
    t0 = fmaxf(fmaxf(t0, sc[1][3]), sc[2][0]);                                \
    t0 = fmaxf(fmaxf(t0, sc[2][1]), sc[2][2]);                                \
    t0 = fmaxf(fmaxf(t0, sc[2][3]), sc[3][0]);                                \
    t0 = fmaxf(fmaxf(t0, sc[3][1]), sc[3][2]);                                \
    float tmax = fmaxf(t0, sc[3][3]);                                         \
    tmax = fmaxf(tmax, __shfl_xor(tmax, 16));                                 \
    tmax = fmaxf(tmax, __shfl_xor(tmax, 32));                                 \
    if (__ballot(tmax > mrun + 8.0f)) {                                       \
      const float mnew = fmaxf(mrun, tmax);                                   \
      const float f = exp2f(mrun - mnew);                                     \
      mrun = mnew;                                                            \
      lrun *= f;                                                              \
      _Pragma("unroll") for (int nb = 0; nb < 4; ++nb)                        \
        _Pragma("unroll") for (int r = 0; r < 4; ++r) acco[nb][r] *= f;       \
    }                                                                         \
    float p[4][4], rs = 0.f;                                                  \
    _Pragma("unroll") for (int nb = 0; nb < 4; ++nb)                          \
      _Pragma("unroll") for (int r = 0; r < 4; ++r) {                         \
        p[nb][r] = exp2f(sc[nb][r] - mrun);                                   \
        rs += p[nb][r];                                                       \
      }                                                                       \
    rs += __shfl_xor(rs, 16);                                                 \
    rs += __shfl_xor(rs, 32);                                                 \
    lrun += rs;                                                               \
    _Pragma("unroll") for (int nb = 0; nb < 4; ++nb) {                        \
      union { u16 u[4]; uint2 v; } pk;                                        \
      _Pragma("unroll") for (int r = 0; r < 4; ++r) pk.u[r] = f2b(p[nb][r]);  \
      const int cc = (nb * 2 + (l4 >> 1)) ^ (l15 & 7);                        \
      *(uint2*)&Ps[w][l15 * 64 + cc * 8 + (l4 & 1) * 4] = pk.v;               \
    }                                                                         \
  }

#define PVSTEP(vi)                                                            \
  {                                                                           \
    __builtin_amdgcn_s_setprio(1);                                            \
    _Pragma("unroll") for (int kc = 0; kc < 2; ++kc) {                        \
      const int ccp = (kc * 4 + l4) ^ (l15 & 7);                              \
      const short8 pf = *(const short8*)&Ps[w][l15 * 64 + ccp * 8];           \
      _Pragma("unroll") for (int nb = 0; nb < 4; ++nb) {                      \
        const int h = nb * 16 + l15;                                          \
        const int cv = (kc * 4 + l4) ^ (l15 & 7);                             \
        const short8 vf =                                                     \
            *(const short8*)&Vs[(vi) * 4096 + h * 64 + cv * 8];               \
        acco[nb] = __builtin_amdgcn_mfma_f32_16x16x32_bf16(vf, pf, acco[nb],  \
                                                            0, 0, 0);         \
      }                                                                       \
    }                                                                         \
    __builtin_amdgcn_s_setprio(0);                                            \
  }

  // prologue: tile0 -> K0/V0; QK^T(0); issue tile1 -> K1/V1
  STAGEK(0, 0); STAGEV(0, 0);
  asm volatile("s_waitcnt vmcnt(0)" ::: "memory");
  __syncthreads();

  f32x4 acco[4];
#pragma unroll
  for (int i = 0; i < 4; ++i) acco[i] = zero4();
  float mrun = -1e30f, lrun = 0.f;

  f32x4 scA[4], scB[4];
  QKT(Ks[0], scA);
  STAGEK(1, 1); STAGEV(1, 1);

  int va = 0, vb = 1, vc = 2;  // V slots of tiles t, t+1, t+2 (t = 2*t2)
  for (int t2 = 0; t2 < 16; ++t2) {
    const int t = 2 * t2;
    // ---- tile t (scA in flight), overlap QK^T(t+1) with softmax(t) ----
    asm volatile("s_waitcnt vmcnt(0)" ::: "memory");
    __syncthreads();                       // tile t+1 landed; QKT(t) done everywhere
    QKT(Ks[1], scB);                       // MFMA pipe: tile t+1
    if (t + 2 < 32) { STAGEK(t + 2, 0); STAGEV(t + 2, vc); }
    SOFTMAX_P(scA);                        // VALU pipe: tile t
    PVSTEP(va);                            // MFMA: PV(t)
    // ---- tile t+1 (scB), overlap QK^T(t+2) with softmax(t+1) ----
    if (t2 < 15) {
      asm volatile("s_waitcnt vmcnt(0)" ::: "memory");
      __syncthreads();                     // tile t+2 landed; QKT(t+1) done
      QKT(Ks[0], scA);                     // tile t+2
      STAGEK(t + 3, 1); STAGEV(t + 3, va); // V[t%3] free: PV(t) already done
      SOFTMAX_P(scB);
      PVSTEP(vb);
      const int ova = va, ovb = vb;        // rotate (va,vb,vc) <- (vc,va,vb)
      va = vc; vb = ova; vc = ovb;
    } else {
      SOFTMAX_P(scB);                      // tail: tile 31
      PVSTEP(vb);
    }
  }
#undef STAGEK
#undef STAGEV
#undef QKT
#undef SOFTMAX_P
#undef PVSTEP

  // epilogue: O[q=l15][h=nb*16+l4*4+r] / lrun -> ao [4096][1024] bf16
  const float inv = 1.f / lrun;
  const int s = qt * 128 + w * 16 + l15;
  u16* __restrict__ dst = aobuf + (size_t)(b * SS + s) * DIM + head * 64;
#pragma unroll
  for (int nb = 0; nb < 4; ++nb) {
    union { u16 u[4]; uint2 v; } pk;
#pragma unroll
    for (int r = 0; r < 4; ++r) pk.u[r] = f2b(acco[nb][r] * inv);
    *(uint2*)&dst[nb * 16 + l4 * 4] = pk.v;
  }
}

// ---------------------------------------------------------------------------
// Proj GEMM bf16 MFMA: ao [4096][1024] x wpt [1024][1024](=w^T) + bias -> fp32
// 128x64 tile, 4 waves; XCD-swizzled 1D grid (512 = 8*64), 2 blocks/CU.
// ---------------------------------------------------------------------------
__global__ __launch_bounds__(256) void gemm_proj_bf16(
    const u16* __restrict__ ao, const u16* __restrict__ wpt,
    const float* __restrict__ bias, float* __restrict__ out) {
  __shared__ __align__(16) u16 As[128 * 64];
  __shared__ __align__(16) u16 Bs[64 * 64];
  const int tid = threadIdx.x, w = tid >> 6, lane = tid & 63;
  const int l15 = lane & 15, l4 = lane >> 4;
  const int lin = blockIdx.x;
  const int swz = (lin & 7) * 64 + (lin >> 3);   // XCD chunk = 2 n-bands x 32 m
  const int m0 = (swz & 31) * 128, n0 = (swz >> 5) * 64;
  const int wm = (w >> 1) * 64, wn = (w & 1) * 32;

  f32x4 acc[4][2];
#pragma unroll
  for (int i = 0; i < 4; ++i)
#pragma unroll
    for (int j = 0; j < 2; ++j) acc[i][j] = zero4();

  for (int k0 = 0; k0 < DIM; k0 += 64) {
#pragma unroll
    for (int j = 0; j < 4; ++j) {
      const int rowA = (w * 4 + j) * 8 + (lane >> 3);
      GLD_LDS16(&ao[(size_t)(m0 + rowA) * DIM + k0 + (lane & 7) * 8],
                &As[(w * 4 + j) * 512]);
    }
#pragma unroll
    for (int j = 0; j < 2; ++j) {
      const int rowB = (w * 2 + j) * 8 + (lane >> 3);
      GLD_LDS16(&wpt[(size_t)(n0 + rowB) * DIM + k0 + (lane & 7) * 8],
                &Bs[(w * 2 + j) * 512]);
    }
    asm volatile("s_waitcnt vmcnt(0)" ::: "memory");
    __syncthreads();
#pragma unroll
    for (int kc = 0; kc < 2; ++kc) {
      short8 af[4], bfr[2];
#pragma unroll
      for (int mb = 0; mb < 4; ++mb)
        af[mb] = *(const short8*)&As[(wm + mb * 16 + l15) * 64 + kc * 32 + l4 * 8];
#pragma unroll
      for (int nb = 0; nb < 2; ++nb)
        bfr[nb] = *(const short8*)&Bs[(wn + nb * 16 + l15) * 64 + kc * 32 + l4 * 8];
#pragma unroll
      for (int mb = 0; mb < 4; ++mb)
#pragma unroll
        for (int nb = 0; nb < 2; ++nb)
          acc[mb][nb] = __builtin_amdgcn_mfma_f32_16x16x32_bf16(
              af[mb], bfr[nb], acc[mb][nb], 0, 0, 0);
    }
    __syncthreads();
  }
#pragma unroll
  for (int nb = 0; nb < 2; ++nb) {
    const int col = n0 + wn + nb * 16 + l15;
    const float bv = bias[col];
#pragma unroll
    for (int mb = 0; mb < 4; ++mb)
#pragma unroll
      for (int r = 0; r < 4; ++r) {
        const int row = m0 + wm + mb * 16 + l4 * 4 + r;
        out[(size_t)row * DIM + col] = acc[mb][nb][r] + bv;
      }
  }
}

// ---------------------------------------------------------------------------
extern "C" void kernel_launch(void* const* d_in, const int* in_sizes, int n_in,
                              void* d_out, int out_size, void* d_ws, size_t ws_size,
                              hipStream_t stream) {
  const float* x      = (const float*)d_in[0];
  const float* w_qkv  = (const float*)d_in[1];
  const float* b_qkv  = (const float*)d_in[2];
  const float* w_proj = (const float*)d_in[3];
  const float* b_proj = (const float*)d_in[4];
  float* out = (float*)d_out;

  u16* ws = (u16*)d_ws;
  u16* x_bf    = ws;                               // 4096*1024 (reused as ao)
  u16* wqkv_t  = x_bf   + (size_t)MTOT * DIM;      // 3072*1024
  u16* wproj_t = wqkv_t + (size_t)3 * DIM * DIM;   // 1024*1024
  u16* qbuf    = wproj_t + (size_t)DIM * DIM;      // [bh][S][64]
  u16* kbuf    = qbuf + (size_t)MTOT * DIM;        // [bh][S][64]
  u16* vtbuf   = kbuf + (size_t)MTOT * DIM;        // [bh][64][S]
  u16* aobuf   = x_bf;                             // alias: x_bf dead after qkv

  prep_kernel<<<6144, 256, 0, stream>>>(x, w_qkv, w_proj, x_bf, wqkv_t, wproj_t);
  gemm_qkv_bf16<<<768, 256, 0, stream>>>(x_bf, wqkv_t, b_qkv, qbuf, kbuf, vtbuf);
  attn_mfma<<<512, 512, 0, stream>>>(qbuf, kbuf, vtbuf, aobuf);
  gemm_proj_bf16<<<512, 256, 0, stream>>>(aobuf, wproj_t, b_proj, out);
}

// Round 9
// 205.087 us; speedup vs baseline: 1.5179x; 1.0913x over previous
//
#include <hip/hip_runtime.h>
#include <hip/hip_bf16.h>

#define DIM    1024
#define NHEADS 16
#define HDIM   64
#define BB     2
#define SS     2048
#define MTOT   (BB * SS)  // 4096

typedef unsigned short u16;
typedef __attribute__((ext_vector_type(8))) short short8;   // 8 bf16 = 4 VGPR (MFMA A/B frag)
typedef __attribute__((ext_vector_type(4))) float f32x4;    // MFMA C/D frag

__device__ inline u16 f2b(float f) {
  __hip_bfloat16 h = __float2bfloat16(f);
  return *reinterpret_cast<u16*>(&h);
}
__device__ inline f32x4 zero4() { f32x4 v = {0.f, 0.f, 0.f, 0.f}; return v; }

// async global->LDS, 16B per lane; LDS dest = wave-uniform base + lane*16
#define GLD_LDS16(GP, LP)                                                   \
  __builtin_amdgcn_global_load_lds(                                         \
      (const __attribute__((address_space(1))) unsigned int*)               \
          (unsigned long long)(const void*)(GP),                            \
      (__attribute__((address_space(3))) unsigned int*)                     \
          (unsigned int)(unsigned long long)(const void*)(LP),              \
      16, 0, 0)

#define QSCALE 0.18033688011112042f  // 0.125 * log2(e): exp2 domain, exact softmax

// ---------------------------------------------------------------------------
// Fused prep: [0,2048)   cast x fp32->bf16 (8 elems/thread)
//             [2048,5120) transpose+cast w_qkv [1024][3072] -> [3072][1024]
//             [5120,6144) transpose+cast w_proj [1024][1024] -> [1024][1024]
// ---------------------------------------------------------------------------
__global__ __launch_bounds__(256) void prep_kernel(
    const float* __restrict__ x, const float* __restrict__ wq,
    const float* __restrict__ wp,
    u16* __restrict__ x_bf, u16* __restrict__ wqt, u16* __restrict__ wpt) {
  __shared__ u16 tile[32][36];
  const int t   = threadIdx.x;
  const int blk = blockIdx.x;
  if (blk < 2048) {
    const int i = blk * 256 + t;
    const float4 a = ((const float4*)x)[i * 2];
    const float4 b = ((const float4*)x)[i * 2 + 1];
    union { u16 u[8]; uint4 v; } r;
    r.u[0] = f2b(a.x); r.u[1] = f2b(a.y); r.u[2] = f2b(a.z); r.u[3] = f2b(a.w);
    r.u[4] = f2b(b.x); r.u[5] = f2b(b.y); r.u[6] = f2b(b.z); r.u[7] = f2b(b.w);
    ((uint4*)x_bf)[i] = r.v;
    return;
  }
  const float* __restrict__ in;
  u16* __restrict__ out;
  int N, n0, k0;
  if (blk < 5120) {
    const int b2 = blk - 2048;
    in = wq; out = wqt; N = 3072;
    n0 = (b2 % 96) * 32; k0 = (b2 / 96) * 32;
  } else {
    const int b2 = blk - 5120;
    in = wp; out = wpt; N = 1024;
    n0 = (b2 & 31) * 32; k0 = (b2 >> 5) * 32;
  }
  const int tr = t >> 3, tc4 = (t & 7) * 4;
  const float4 a = *(const float4*)&in[(size_t)(k0 + tr) * N + n0 + tc4];
  tile[tr][tc4 + 0] = f2b(a.x); tile[tr][tc4 + 1] = f2b(a.y);
  tile[tr][tc4 + 2] = f2b(a.z); tile[tr][tc4 + 3] = f2b(a.w);
  __syncthreads();
  union { u16 u[4]; uint2 v; } pk;
  pk.u[0] = tile[tc4 + 0][tr]; pk.u[1] = tile[tc4 + 1][tr];
  pk.u[2] = tile[tc4 + 2][tr]; pk.u[3] = tile[tc4 + 3][tr];
  *(uint2*)&out[(size_t)(n0 + tr) * DIM + k0 + tc4] = pk.v;
}

// ---------------------------------------------------------------------------
// QKV GEMM bf16 MFMA v2: 2-phase double-buffered staging (the R4 attn fix,
// finally applied here — the old loop exposed full load latency on every one
// of the 16 K-steps: STAGE->vmcnt(0)->barrier->compute).
// New loop: STAGE(t+1, buf^1) BEFORE compute(t); one vmcnt(0)+barrier per
// step AFTER compute — latency hides under MFMA+ds_read.
// xa [4096][1024] x wt [3072][1024](=w^T) + bias.
// Q -> qbuf [bh][S][64] scaled; K -> kbuf [bh][S][64]; V -> vtbuf [bh][64][S]
// via swizzled-LDS repack (coalesced dwordx4 stores).
// 128x128 tile, BK=64, 4 waves. LDS 64KB -> 2 blocks/CU; launch_bounds(256,2)
// keeps VGPR cap at 256 (R3 spill lesson). XCD-swizzled grid (768 = 8*96).
// ---------------------------------------------------------------------------
__global__ __launch_bounds__(256, 2) void gemm_qkv_bf16(
    const u16* __restrict__ xa, const u16* __restrict__ wt,
    const float* __restrict__ bias,
    u16* __restrict__ qbuf, u16* __restrict__ kbuf, u16* __restrict__ vtbuf) {
  __shared__ __align__(16) u16 lds[32768];   // As[2]: [0,16384)  Bs[2]: [16384,32768)
  u16* __restrict__ AsB = lds;
  u16* __restrict__ BsB = lds + 16384;
  const int tid = threadIdx.x, w = tid >> 6, lane = tid & 63;
  const int l15 = lane & 15, l4 = lane >> 4;
  const int lin = blockIdx.x;
  const int swz = (lin & 7) * 96 + (lin >> 3);   // XCD chunk = 3 n-bands x 32 m
  const int m0 = (swz & 31) * 128, n0 = (swz >> 5) * 128;
  const int wm = (w >> 1) * 64, wn = (w & 1) * 64;

  f32x4 acc[4][4];
#pragma unroll
  for (int i = 0; i < 4; ++i)
#pragma unroll
    for (int j = 0; j < 4; ++j) acc[i][j] = zero4();

#define STAGEG(kk, bi)                                                        \
  _Pragma("unroll") for (int j = 0; j < 4; ++j) {                             \
    const int rowX = (w * 4 + j) * 8 + (lane >> 3);                           \
    const int kcol = (kk) * 64 + (lane & 7) * 8;                              \
    GLD_LDS16(&xa[(size_t)(m0 + rowX) * DIM + kcol],                          \
              &AsB[(bi) * 8192 + (w * 4 + j) * 512]);                         \
    GLD_LDS16(&wt[(size_t)(n0 + rowX) * DIM + kcol],                          \
              &BsB[(bi) * 8192 + (w * 4 + j) * 512]);                         \
  }

  STAGEG(0, 0);
  asm volatile("s_waitcnt vmcnt(0)" ::: "memory");
  __syncthreads();

  for (int kk = 0; kk < 16; ++kk) {
    const int cur = kk & 1;
    if (kk + 1 < 16) STAGEG(kk + 1, 1 - cur);   // flies under compute
    const u16* __restrict__ As = AsB + cur * 8192;
    const u16* __restrict__ Bs = BsB + cur * 8192;
#pragma unroll
    for (int kc = 0; kc < 2; ++kc) {
      short8 af[4], bfr[4];
#pragma unroll
      for (int mb = 0; mb < 4; ++mb)
        af[mb] = *(const short8*)&As[(wm + mb * 16 + l15) * 64 + kc * 32 + l4 * 8];
#pragma unroll
      for (int nb = 0; nb < 4; ++nb)
        bfr[nb] = *(const short8*)&Bs[(wn + nb * 16 + l15) * 64 + kc * 32 + l4 * 8];
#pragma unroll
      for (int mb = 0; mb < 4; ++mb)
#pragma unroll
        for (int nb = 0; nb < 4; ++nb)
          acc[mb][nb] = __builtin_amdgcn_mfma_f32_16x16x32_bf16(
              af[mb], bfr[nb], acc[mb][nb], 0, 0, 0);
    }
    asm volatile("s_waitcnt vmcnt(0)" ::: "memory");
    __syncthreads();
  }
#undef STAGEG

  const int colb  = n0 + wn;
  const int which = colb >> 10;
  const int head  = (colb & 1023) >> 6;
  if (which == 2) {
    // V^T path via LDS repack (wave-private 64x64 region carved from lds;
    // all compute done after the loop's final barrier). 16B-chunk XOR swizzle
    // keeps ds_write_b64 and ds_read_b128 conflict-free.
    u16* __restrict__ wl = lds + w * 4096;
    const int rowbase = m0 + wm;                 // 64-aligned
    const int bidx = rowbase >> 11, sbase = rowbase & 2047;
    float bv[4];
#pragma unroll
    for (int nb = 0; nb < 4; ++nb) bv[nb] = bias[colb + nb * 16 + l15];
#pragma unroll
    for (int nb = 0; nb < 4; ++nb) {
      const int h = nb * 16 + l15;
#pragma unroll
      for (int mb = 0; mb < 4; ++mb) {
        union { u16 u[4]; uint2 v; } pk;
#pragma unroll
        for (int r = 0; r < 4; ++r) pk.u[r] = f2b(acc[mb][nb][r] + bv[nb]);
        const int csw = (mb * 2 + (l4 >> 1)) ^ (l15 & 7);
        *(uint2*)&wl[h * 64 + csw * 8 + (l4 & 1) * 4] = pk.v;
      }
    }
    // wave-private: program order + compiler lgkmcnt suffice (no barrier)
#pragma unroll
    for (int p = 0; p < 8; ++p) {
      const int h = (lane >> 3) + p * 8;
      const int csw = (lane & 7) ^ (h & 7);
      const uint4 d = *(const uint4*)&wl[h * 64 + csw * 8];
      *(uint4*)&vtbuf[((size_t)((bidx * NHEADS + head) * 64 + h)) * SS +
                      sbase + (lane & 7) * 8] = d;
    }
  } else {
    u16* __restrict__ dst = (which == 0) ? qbuf : kbuf;
    const float scale = (which == 0) ? QSCALE : 1.0f;
#pragma unroll
    for (int nb = 0; nb < 4; ++nb) {
      const int col = colb + nb * 16 + l15;
      const float bv = bias[col];
      const int h = col & 63;
#pragma unroll
      for (int mb = 0; mb < 4; ++mb)
#pragma unroll
        for (int r = 0; r < 4; ++r) {
          const int row = m0 + wm + mb * 16 + l4 * 4 + r;
          const int b = row >> 11, s = row & 2047;
          dst[((size_t)((b * NHEADS + head) * SS + s)) * 64 + h] =
              f2b((acc[mb][nb][r] + bv) * scale);
        }
    }
  }
}

// ---------------------------------------------------------------------------
// Flash attention bf16 MFMA (unchanged from R7 — isolating the GEMM change).
// QBLK=128 (8 waves, 512 thr), KVBLK=64; S^T=mfma(K,Q), O^T=mfma(V,P).
// K double-buffered, V triple-buffered; gld_lds staging with source-side XOR
// swizzle; 1 vmcnt0+barrier per tile; exp2 softmax; defer-max THR=8.
// ---------------------------------------------------------------------------
__global__ __launch_bounds__(512, 4) void attn_mfma(
    const u16* __restrict__ qbuf, const u16* __restrict__ kbuf,
    const u16* __restrict__ vtbuf, u16* __restrict__ aobuf) {
  __shared__ __align__(16) u16 Ks[2][64 * 64];
  __shared__ __align__(16) u16 Vs[3 * 64 * 64];
  __shared__ __align__(16) u16 Ps[8][16 * 64];
  const int tid = threadIdx.x, w = tid >> 6, lane = tid & 63;
  const int l15 = lane & 15, l4 = lane >> 4;
  const int lin = blockIdx.x;
  const int swz = (lin & 7) * 64 + (lin >> 3);   // XCD chunk = 4 bh x 16 qt
  const int bh = swz >> 4, qt = swz & 15;
  const int b = bh >> 4, head = bh & 15;

  const u16* __restrict__ qsrc  = qbuf + ((size_t)(bh * SS + qt * 128 + w * 16)) * 64;
  const u16* __restrict__ kbase = kbuf + (size_t)bh * SS * 64;
  const u16* __restrict__ vtb   = vtbuf + (size_t)bh * 64 * SS;

  short8 qf[2];
#pragma unroll
  for (int kc = 0; kc < 2; ++kc)
    qf[kc] = *(const short8*)&qsrc[l15 * 64 + kc * 32 + l4 * 8];

  const int srow  = w * 8 + (lane >> 3);
  const int schk  = (lane & 7) ^ (srow & 7);

#define STAGEK(t, bi)                                                         \
  GLD_LDS16(kbase + ((size_t)((t) * 64 + srow)) * 64 + schk * 8,              \
            &Ks[bi][w * 8 * 64]);
#define STAGEV(t, vi)                                                         \
  GLD_LDS16(vtb + (size_t)srow * SS + (t) * 64 + schk * 8,                    \
            &Vs[(vi) * 4096 + w * 8 * 64]);

#define QKT(KB, sc)                                                           \
  {                                                                           \
    _Pragma("unroll") for (int i = 0; i < 4; ++i) sc[i] = zero4();            \
    __builtin_amdgcn_s_setprio(1);                                            \
    _Pragma("unroll") for (int kc = 0; kc < 2; ++kc)                          \
      _Pragma("unroll") for (int nb = 0; nb < 4; ++nb) {                      \
        const int key = nb * 16 + l15;                                        \
        const int cc = (kc * 4 + l4) ^ (l15 & 7);                             \
        const short8 kf = *(const short8*)&(KB)[key * 64 + cc * 8];           \
        sc[nb] = __builtin_amdgcn_mfma_f32_16x16x32_bf16(kf, qf[kc], sc[nb],  \
                                                          0, 0, 0);           \
      }                                                                       \
    __builtin_amdgcn_s_setprio(0);                                            \
  }

#define SOFTMAX_P(sc)                                                         \
  {                                                                           \
    float t0 = fmaxf(fmaxf(sc[0][0], sc[0][1]), sc[0][2]);                    \
    t0 = fmaxf(fmaxf(t0, sc[0][3]), sc[1][0]);                                \
    t0 = fmaxf(fmaxf(t0, sc[1][1]), sc[1][2]);                                \
    t0 = fmaxf(fmaxf(t0, sc[1][3]), sc[2][0]);                                \
    t0 = fmaxf(fmaxf(t0, sc[2][1]), sc[2][2]);                                \
    t0 = fmaxf(fmaxf(t0, sc[2][3]), sc[3][0]);                                \
    t0 = fmaxf(fmaxf(t0, sc[3][1]), sc[3][2]);                                \
    float tmax = fmaxf(t0, sc[3][3]);                                         \
    tmax = fmaxf(tmax, __shfl_xor(tmax, 16));                                 \
    tmax = fmaxf(tmax, __shfl_xor(tmax, 32));                                 \
    if (__ballot(tmax > mrun + 8.0f)) {                                       \
      const float mnew = fmaxf(mrun, tmax);                                   \
      const float f = exp2f(mrun - mnew);                                     \
      mrun = mnew;                                                            \
      lrun *= f;                                                              \
      _Pragma("unroll") for (int nb = 0; nb < 4; ++nb)                        \
        _Pragma("unroll") for (int r = 0; r < 4; ++r) acco[nb][r] *= f;       \
    }                                                                         \
    float p[4][4], rs = 0.f;                                                  \
    _Pragma("unroll") for (int nb = 0; nb < 4; ++nb)                          \
      _Pragma("unroll") for (int r = 0; r < 4; ++r) {                         \
        p[nb][r] = exp2f(sc[nb][r] - mrun);                                   \
        rs += p[nb][r];                                                       \
      }                                                                       \
    rs += __shfl_xor(rs, 16);                                                 \
    rs += __shfl_xor(rs, 32);                                                 \
    lrun += rs;                                                               \
    _Pragma("unroll") for (int nb = 0; nb < 4; ++nb) {                        \
      union { u16 u[4]; uint2 v; } pk;                                        \
      _Pragma("unroll") for (int r = 0; r < 4; ++r) pk.u[r] = f2b(p[nb][r]);  \
      const int cc = (nb * 2 + (l4 >> 1)) ^ (l15 & 7);                        \
      *(uint2*)&Ps[w][l15 * 64 + cc * 8 + (l4 & 1) * 4] = pk.v;               \
    }                                                                         \
  }

#define PVSTEP(vi)                                                            \
  {                                                                           \
    __builtin_amdgcn_s_setprio(1);                                            \
    _Pragma("unroll") for (int kc = 0; kc < 2; ++kc) {                        \
      const int ccp = (kc * 4 + l4) ^ (l15 & 7);                              \
      const short8 pf = *(const short8*)&Ps[w][l15 * 64 + ccp * 8];           \
      _Pragma("unroll") for (int nb = 0; nb < 4; ++nb) {                      \
        const int h = nb * 16 + l15;                                          \
        const int cv = (kc * 4 + l4) ^ (l15 & 7);                             \
        const short8 vf =                                                     \
            *(const short8*)&Vs[(vi) * 4096 + h * 64 + cv * 8];               \
        acco[nb] = __builtin_amdgcn_mfma_f32_16x16x32_bf16(vf, pf, acco[nb],  \
                                                            0, 0, 0);         \
      }                                                                       \
    }                                                                         \
    __builtin_amdgcn_s_setprio(0);                                            \
  }

  // prologue: tile0 -> K0/V0; QK^T(0); issue tile1 -> K1/V1
  STAGEK(0, 0); STAGEV(0, 0);
  asm volatile("s_waitcnt vmcnt(0)" ::: "memory");
  __syncthreads();

  f32x4 acco[4];
#pragma unroll
  for (int i = 0; i < 4; ++i) acco[i] = zero4();
  float mrun = -1e30f, lrun = 0.f;

  f32x4 scA[4], scB[4];
  QKT(Ks[0], scA);
  STAGEK(1, 1); STAGEV(1, 1);

  int va = 0, vb = 1, vc = 2;  // V slots of tiles t, t+1, t+2 (t = 2*t2)
  for (int t2 = 0; t2 < 16; ++t2) {
    const int t = 2 * t2;
    asm volatile("s_waitcnt vmcnt(0)" ::: "memory");
    __syncthreads();                       // tile t+1 landed; QKT(t) done everywhere
    QKT(Ks[1], scB);                       // MFMA pipe: tile t+1
    if (t + 2 < 32) { STAGEK(t + 2, 0); STAGEV(t + 2, vc); }
    SOFTMAX_P(scA);                        // VALU pipe: tile t
    PVSTEP(va);                            // MFMA: PV(t)
    if (t2 < 15) {
      asm volatile("s_waitcnt vmcnt(0)" ::: "memory");
      __syncthreads();                     // tile t+2 landed; QKT(t+1) done
      QKT(Ks[0], scA);                     // tile t+2
      STAGEK(t + 3, 1); STAGEV(t + 3, va); // V[t%3] free: PV(t) already done
      SOFTMAX_P(scB);
      PVSTEP(vb);
      const int ova = va, ovb = vb;        // rotate (va,vb,vc) <- (vc,va,vb)
      va = vc; vb = ova; vc = ovb;
    } else {
      SOFTMAX_P(scB);                      // tail: tile 31
      PVSTEP(vb);
    }
  }
#undef STAGEK
#undef STAGEV
#undef QKT
#undef SOFTMAX_P
#undef PVSTEP

  // epilogue: O[q=l15][h=nb*16+l4*4+r] / lrun -> ao [4096][1024] bf16
  const float inv = 1.f / lrun;
  const int s = qt * 128 + w * 16 + l15;
  u16* __restrict__ dst = aobuf + (size_t)(b * SS + s) * DIM + head * 64;
#pragma unroll
  for (int nb = 0; nb < 4; ++nb) {
    union { u16 u[4]; uint2 v; } pk;
#pragma unroll
    for (int r = 0; r < 4; ++r) pk.u[r] = f2b(acco[nb][r] * inv);
    *(uint2*)&dst[nb * 16 + l4 * 4] = pk.v;
  }
}

// ---------------------------------------------------------------------------
// Proj GEMM bf16 MFMA v2: same 2-phase double-buffered staging.
// ao [4096][1024] x wpt [1024][1024](=w^T) + bias -> fp32 out.
// 128x64 tile, 4 waves; LDS 48KB -> 3 blocks/CU (launch_bounds(256,3));
// XCD-swizzled 1D grid (512 = 8*64).
// ---------------------------------------------------------------------------
__global__ __launch_bounds__(256, 3) void gemm_proj_bf16(
    const u16* __restrict__ ao, const u16* __restrict__ wpt,
    const float* __restrict__ bias, float* __restrict__ out) {
  __shared__ __align__(16) u16 lds[24576];   // As[2]: [0,16384)  Bs[2]: [16384,24576)
  u16* __restrict__ AsB = lds;
  u16* __restrict__ BsB = lds + 16384;
  const int tid = threadIdx.x, w = tid >> 6, lane = tid & 63;
  const int l15 = lane & 15, l4 = lane >> 4;
  const int lin = blockIdx.x;
  const int swz = (lin & 7) * 64 + (lin >> 3);   // XCD chunk = 2 n-bands x 32 m
  const int m0 = (swz & 31) * 128, n0 = (swz >> 5) * 64;
  const int wm = (w >> 1) * 64, wn = (w & 1) * 32;

  f32x4 acc[4][2];
#pragma unroll
  for (int i = 0; i < 4; ++i)
#pragma unroll
    for (int j = 0; j < 2; ++j) acc[i][j] = zero4();

#define STAGEP(kk, bi)                                                        \
  _Pragma("unroll") for (int j = 0; j < 4; ++j) {                             \
    const int rowA = (w * 4 + j) * 8 + (lane >> 3);                           \
    GLD_LDS16(&ao[(size_t)(m0 + rowA) * DIM + (kk) * 64 + (lane & 7) * 8],    \
              &AsB[(bi) * 8192 + (w * 4 + j) * 512]);                         \
  }                                                                           \
  _Pragma("unroll") for (int j = 0; j < 2; ++j) {                             \
    const int rowB = (w * 2 + j) * 8 + (lane >> 3);                           \
    GLD_LDS16(&wpt[(size_t)(n0 + rowB) * DIM + (kk) * 64 + (lane & 7) * 8],   \
              &BsB[(bi) * 4096 + (w * 2 + j) * 512]);                         \
  }

  STAGEP(0, 0);
  asm volatile("s_waitcnt vmcnt(0)" ::: "memory");
  __syncthreads();

  for (int kk = 0; kk < 16; ++kk) {
    const int cur = kk & 1;
    if (kk + 1 < 16) STAGEP(kk + 1, 1 - cur);   // flies under compute
    const u16* __restrict__ As = AsB + cur * 8192;
    const u16* __restrict__ Bs = BsB + cur * 4096;
#pragma unroll
    for (int kc = 0; kc < 2; ++kc) {
      short8 af[4], bfr[2];
#pragma unroll
      for (int mb = 0; mb < 4; ++mb)
        af[mb] = *(const short8*)&As[(wm + mb * 16 + l15) * 64 + kc * 32 + l4 * 8];
#pragma unroll
      for (int nb = 0; nb < 2; ++nb)
        bfr[nb] = *(const short8*)&Bs[(wn + nb * 16 + l15) * 64 + kc * 32 + l4 * 8];
#pragma unroll
      for (int mb = 0; mb < 4; ++mb)
#pragma unroll
        for (int nb = 0; nb < 2; ++nb)
          acc[mb][nb] = __builtin_amdgcn_mfma_f32_16x16x32_bf16(
              af[mb], bfr[nb], acc[mb][nb], 0, 0, 0);
    }
    asm volatile("s_waitcnt vmcnt(0)" ::: "memory");
    __syncthreads();
  }
#undef STAGEP

#pragma unroll
  for (int nb = 0; nb < 2; ++nb) {
    const int col = n0 + wn + nb * 16 + l15;
    const float bv = bias[col];
#pragma unroll
    for (int mb = 0; mb < 4; ++mb)
#pragma unroll
      for (int r = 0; r < 4; ++r) {
        const int row = m0 + wm + mb * 16 + l4 * 4 + r;
        out[(size_t)row * DIM + col] = acc[mb][nb][r] + bv;
      }
  }
}

// ---------------------------------------------------------------------------
extern "C" void kernel_launch(void* const* d_in, const int* in_sizes, int n_in,
                              void* d_out, int out_size, void* d_ws, size_t ws_size,
                              hipStream_t stream) {
  const float* x      = (const float*)d_in[0];
  const float* w_qkv  = (const float*)d_in[1];
  const float* b_qkv  = (const float*)d_in[2];
  const float* w_proj = (const float*)d_in[3];
  const float* b_proj = (const float*)d_in[4];
  float* out = (float*)d_out;

  u16* ws = (u16*)d_ws;
  u16* x_bf    = ws;                               // 4096*1024 (reused as ao)
  u16* wqkv_t  = x_bf   + (size_t)MTOT * DIM;      // 3072*1024
  u16* wproj_t = wqkv_t + (size_t)3 * DIM * DIM;   // 1024*1024
  u16* qbuf    = wproj_t + (size_t)DIM * DIM;      // [bh][S][64]
  u16* kbuf    = qbuf + (size_t)MTOT * DIM;        // [bh][S][64]
  u16* vtbuf   = kbuf + (size_t)MTOT * DIM;        // [bh][64][S]
  u16* aobuf   = x_bf;                             // alias: x_bf dead after qkv

  prep_kernel<<<6144, 256, 0, stream>>>(x, w_qkv, w_proj, x_bf, wqkv_t, wproj_t);
  gemm_qkv_bf16<<<768, 256, 0, stream>>>(x_bf, wqkv_t, b_qkv, qbuf, kbuf, vtbuf);
  attn_mfma<<<512, 512, 0, stream>>>(qbuf, kbuf, vtbuf, aobuf);
  gemm_proj_bf16<<<512, 256, 0, stream>>>(aobuf, wproj_t, b_proj, out);
}